// Round 3
// baseline (3606.588 us; speedup 1.0000x reference)
//
#include <hip/hip_runtime.h>
#include <hip/hip_bf16.h>

#define NODES  16000
#define FDIM   128
#define EDGES  256000
#define NNZ_   512000
#define CH     32000     // per-edge chunk size (8 chunks)

__device__ __forceinline__ float sigmoidf_(float z) { return 1.f / (1.f + __expf(-z)); }

// ---------------- HyperWeight: node_w[n] = sigmoid(relu([x|proto]@W1+b1)@W2+b2) -------------
__global__ __launch_bounds__(128) void hyperweight_k(
    const float* __restrict__ x, const float* __restrict__ ge, const int* __restrict__ batch,
    const float* __restrict__ w1, const float* __restrict__ b1,
    const float* __restrict__ w2, const float* __restrict__ b2, float* __restrict__ node_w)
{
    __shared__ float a[8][256];
    __shared__ float red[128];
    const int t = threadIdx.x;
    const int nb = blockIdx.x * 8;
    for (int u = 0; u < 8; ++u) {
        int n = nb + u;
        a[u][t]       = x[(size_t)n * FDIM + t];
        a[u][128 + t] = ge[(size_t)batch[n] * FDIM + t];
    }
    __syncthreads();
    float acc[8] = {0,0,0,0,0,0,0,0};
    for (int k = 0; k < 256; ++k) {
        float wv = w1[k * 128 + t];
        #pragma unroll
        for (int u = 0; u < 8; ++u) acc[u] += a[u][k] * wv;
    }
    const float wv2 = w2[t];
    for (int u = 0; u < 8; ++u) {
        float h = fmaxf(acc[u] + b1[t], 0.f);
        red[t] = h * wv2;
        __syncthreads();
        for (int s2 = 64; s2 > 0; s2 >>= 1) {
            if (t < s2) red[t] += red[t + s2];
            __syncthreads();
        }
        if (t == 0) node_w[nb + u] = sigmoidf_(red[0] + b2[0]);
        __syncthreads();
    }
}

// ---------------- incidence pass: D, Bcnt, rowCnt ----------------
__global__ void incidence_pass(const int* __restrict__ he, const float* __restrict__ node_w,
                               float* __restrict__ D, int* __restrict__ Bcnt, int* __restrict__ rowCnt)
{
    int i = blockIdx.x * 256 + threadIdx.x;
    if (i >= NNZ_) return;
    int hr = he[i];
    int hc = he[NNZ_ + i];
    int hc2 = he[NNZ_ + hc];              // repo quirk: w = node_w[hcol[hcol[i]]]
    atomicAdd(&D[hr], node_w[hc2]);
    atomicAdd(&Bcnt[hc], 1);
    atomicAdd(&rowCnt[hr], 1);
}

__global__ void dinv_k(float* __restrict__ D) {
    int e = blockIdx.x * 256 + threadIdx.x;
    if (e >= EDGES) return;
    float d = D[e];
    D[e] = (d != 0.f) ? 1.f / d : 0.f;
}
__global__ void binv_k(const int* __restrict__ Bcnt, float* __restrict__ Binv) {
    int n = blockIdx.x * 256 + threadIdx.x;
    if (n >= NODES) return;
    int c = Bcnt[n];
    Binv[n] = c ? 1.f / (float)c : 0.f;
}

// ---------------- exclusive scan (3-kernel) ----------------
__global__ __launch_bounds__(1024) void reduce_chunks(const int* __restrict__ in, int* __restrict__ part, int n) {
    __shared__ int s[1024];
    int t = threadIdx.x, g = blockIdx.x * 1024 + t;
    s[t] = (g < n) ? in[g] : 0;
    __syncthreads();
    for (int d = 512; d > 0; d >>= 1) {
        if (t < d) s[t] += s[t + d];
        __syncthreads();
    }
    if (t == 0) part[blockIdx.x] = s[0];
}
__global__ __launch_bounds__(1024) void scan_sums(int* __restrict__ part, int nc) {
    __shared__ int s[1024];
    int t = threadIdx.x;
    int v = (t < nc) ? part[t] : 0;
    s[t] = v;
    __syncthreads();
    for (int d = 1; d < 1024; d <<= 1) {
        int tv = (t >= d) ? s[t - d] : 0;
        __syncthreads();
        s[t] += tv;
        __syncthreads();
    }
    if (t < nc) part[t] = s[t] - v;     // exclusive
}
__global__ __launch_bounds__(1024) void scan_chunks(const int* __restrict__ in, const int* __restrict__ part,
                                                    int* __restrict__ out, int n) {
    __shared__ int s[1024];
    int t = threadIdx.x, g = blockIdx.x * 1024 + t;
    int v = (g < n) ? in[g] : 0;
    s[t] = v;
    __syncthreads();
    for (int d = 1; d < 1024; d <<= 1) {
        int tv = (t >= d) ? s[t - d] : 0;
        __syncthreads();
        s[t] += tv;
        __syncthreads();
    }
    int excl = s[t] - v + part[blockIdx.x];
    if (g < n) out[g] = excl;
    if (g == n - 1) out[n] = excl + v;
}

// ---------------- scatter into CSR lists ----------------
__global__ void scatter_pass(const int* __restrict__ he, const int* __restrict__ colOff, const int* __restrict__ rowOff,
                             int* __restrict__ colCur, int* __restrict__ rowCur,
                             int* __restrict__ colList, int* __restrict__ rowList)
{
    int i = blockIdx.x * 256 + threadIdx.x;
    if (i >= NNZ_) return;
    int hr = he[i];
    int hc = he[NNZ_ + i];
    int p = colOff[hc] + atomicAdd(&colCur[hc], 1);
    colList[p] = hr;
    int q = rowOff[hr] + atomicAdd(&rowCur[hr], 1);
    rowList[q] = hc;
}

// ---------------- agg1[n,256] = sum over edges r in col(n) of [x[ei0[r]] | x[ei1[r]]] ------
__global__ __launch_bounds__(256) void col_gather_x(
    const float* __restrict__ x, const int* __restrict__ ei,
    const int* __restrict__ colOff, const int* __restrict__ colList, float* __restrict__ agg)
{
    int n = blockIdx.x;
    int t = threadIdx.x;
    int base = (t < FDIM) ? 0 : EDGES;
    int f = t & (FDIM - 1);
    int s = colOff[n], e = colOff[n + 1];
    float acc = 0.f;
    for (int j = s; j < e; ++j) {
        int r = colList[j];
        int id = ei[base + r];
        acc += x[(size_t)id * FDIM + f];
    }
    agg[(size_t)n * 256 + t] = acc;
}

// ---------------- agg2[n,256] = sum over r in col(n) of er[r], er recomputed on the fly ----
__global__ __launch_bounds__(256) void col_gather_er(
    const float* __restrict__ oe1, const float* __restrict__ Dinv, const float* __restrict__ c1b,
    const int* __restrict__ colOff, const int* __restrict__ colList,
    const int* __restrict__ rowOff, const int* __restrict__ rowList, float* __restrict__ agg)
{
    int n = blockIdx.x;
    int t = threadIdx.x;
    int s = colOff[n], e = colOff[n + 1];
    float b = c1b[t];
    float acc = 0.f;
    for (int j = s; j < e; ++j) {
        int r = colList[j];
        int rs = rowOff[r], re = rowOff[r + 1];
        float v = 0.f;
        for (int q = rs; q < re; ++q)
            v += oe1[(size_t)rowList[q] * 256 + t];
        acc += sigmoidf_(Dinv[r] * v + b);
    }
    agg[(size_t)n * 256 + t] = acc;
}

// ---------------- node-rows GEMM: C[m,n] = rowscale[m] * (A @ B)[m,n] ----------------
template<int K, int NN>
__global__ __launch_bounds__(256) void gemm_node(
    const float* __restrict__ A, const float* __restrict__ B,
    const float* __restrict__ rowscale, float* __restrict__ C)
{
    __shared__ float As[16][68];
    __shared__ float Bs[16][68];
    const int tid = threadIdx.x;
    const int m0 = blockIdx.x * 64, n0 = blockIdx.y * 64;
    const int la_k = tid & 15, la_m = tid >> 4;
    const int lb_n = tid & 63, lb_k = tid >> 6;
    const int tn = tid & 15, tm = tid >> 4;
    float acc[4][4] = {};
    for (int k0 = 0; k0 < K; k0 += 16) {
        #pragma unroll
        for (int r = 0; r < 4; ++r)
            As[la_k][la_m + 16 * r] = A[(size_t)(m0 + la_m + 16 * r) * K + k0 + la_k];
        #pragma unroll
        for (int r = 0; r < 4; ++r)
            Bs[lb_k + 4 * r][lb_n] = B[(size_t)(k0 + lb_k + 4 * r) * NN + n0 + lb_n];
        __syncthreads();
        #pragma unroll
        for (int kk = 0; kk < 16; ++kk) {
            float4 av = *(const float4*)&As[kk][tm * 4];
            float4 bv = *(const float4*)&Bs[kk][tn * 4];
            float am[4] = {av.x, av.y, av.z, av.w};
            float bn[4] = {bv.x, bv.y, bv.z, bv.w};
            #pragma unroll
            for (int i = 0; i < 4; ++i)
                #pragma unroll
                for (int j = 0; j < 4; ++j)
                    acc[i][j] += am[i] * bn[j];
        }
        __syncthreads();
    }
    #pragma unroll
    for (int i = 0; i < 4; ++i) {
        int m = m0 + tm * 4 + i;
        float rs = rowscale[m];
        float4 o = make_float4(rs * acc[i][0], rs * acc[i][1], rs * acc[i][2], rs * acc[i][3]);
        *(float4*)(C + (size_t)m * NN + n0 + tn * 4) = o;
    }
}

// ---------------- sij[e,128] (bf16) = sigmoid(Dinv[e]*rowsum(oe2) + c2_b) ----------------
__global__ void sij_k(const float* __restrict__ oe2, const int* __restrict__ rowOff,
                      const int* __restrict__ rowList, const float* __restrict__ Dinv,
                      const float* __restrict__ bias, __hip_bfloat16* __restrict__ sij)
{
    int w = (blockIdx.x * 256 + threadIdx.x) >> 6;
    int lane = threadIdx.x & 63;
    if (w >= EDGES) return;
    int s = rowOff[w], t = rowOff[w + 1];
    float2 acc = make_float2(0.f, 0.f);
    for (int j = s; j < t; ++j) {
        int n = rowList[j];
        float2 q = *(const float2*)(oe2 + (size_t)n * 128 + lane * 2);
        acc.x += q.x; acc.y += q.y;
    }
    float dv = Dinv[w];
    float2 b = *(const float2*)(bias + lane * 2);
    __hip_bfloat162 h;
    h.x = __float2bfloat16(sigmoidf_(dv * acc.x + b.x));
    h.y = __float2bfloat16(sigmoidf_(dv * acc.y + b.y));
    *(__hip_bfloat162*)(sij + (size_t)w * 128 + lane * 2) = h;
}

// ---------------- per-edge chunked GEMMs ----------------
enum { EGEN = 0, EDIR = 1, ECLS = 2 };

template<int K, int AMODE, int NN>
__global__ __launch_bounds__(256) void gemm_edge(
    const float* __restrict__ Asrc, const float* __restrict__ B, const float* __restrict__ bias,
    float* __restrict__ C,
    const int* __restrict__ ei, const int* __restrict__ batch,
    const float* __restrict__ x, const float* __restrict__ ge,
    const __hip_bfloat16* __restrict__ sij, const float* __restrict__ attn, int eoff)
{
    __shared__ float As[16][68];
    __shared__ float Bs[16][68];
    const int tid = threadIdx.x;
    const int m0 = blockIdx.x * 64, n0 = blockIdx.y * 64;
    const int la_k = tid & 15, la_m = tid >> 4;
    const int lb_n = tid & 63, lb_k = tid >> 6;
    const int tn = tid & 15, tm = tid >> 4;

    int rA[4], rB[4], rG[4], mg[4];
    #pragma unroll
    for (int r = 0; r < 4; ++r) {
        int mloc = m0 + la_m + 16 * r;
        mg[r] = mloc;
        if constexpr (AMODE == EGEN) {
            int eg = eoff + mloc;
            rA[r] = ei[eg] * FDIM;
            rB[r] = ei[EDGES + eg] * FDIM;
            rG[r] = batch[ei[eg]] * FDIM;
        }
        if constexpr (AMODE == ECLS) {
            int eg = eoff + mloc;
            rG[r] = batch[ei[eg]] * FDIM;
        }
    }
    float a0 = 0.f, a1 = 0.f;
    if constexpr (AMODE == ECLS) { a0 = attn[0]; a1 = attn[1]; }

    float acc[4][4] = {};
    for (int k0 = 0; k0 < K; k0 += 16) {
        #pragma unroll
        for (int r = 0; r < 4; ++r) {
            int k = k0 + la_k;
            float v;
            if constexpr (AMODE == EGEN) {
                v = (k < FDIM) ? x[rA[r] + k]
                  : (k < 2 * FDIM) ? x[rB[r] + k - FDIM]
                  : ge[rG[r] + k - 2 * FDIM];
            } else if constexpr (AMODE == ECLS) {
                v = (k < FDIM)
                  ? (a0 * Asrc[(size_t)mg[r] * FDIM + k]
                     + a1 * __bfloat162float(sij[(size_t)(eoff + mg[r]) * FDIM + k]))
                  : ge[rG[r] + k - FDIM];
            } else {
                v = Asrc[(size_t)mg[r] * K + k];
            }
            As[la_k][la_m + 16 * r] = v;
        }
        #pragma unroll
        for (int r = 0; r < 4; ++r)
            Bs[lb_k + 4 * r][lb_n] = B[(size_t)(k0 + lb_k + 4 * r) * NN + n0 + lb_n];
        __syncthreads();
        #pragma unroll
        for (int kk = 0; kk < 16; ++kk) {
            float4 av = *(const float4*)&As[kk][tm * 4];
            float4 bv = *(const float4*)&Bs[kk][tn * 4];
            float am[4] = {av.x, av.y, av.z, av.w};
            float bn[4] = {bv.x, bv.y, bv.z, bv.w};
            #pragma unroll
            for (int i = 0; i < 4; ++i)
                #pragma unroll
                for (int j = 0; j < 4; ++j)
                    acc[i][j] += am[i] * bn[j];
        }
        __syncthreads();
    }
    #pragma unroll
    for (int i = 0; i < 4; ++i) {
        int m = m0 + tm * 4 + i;
        float4 o;
        float* po = &o.x;
        #pragma unroll
        for (int j = 0; j < 4; ++j) {
            float v = acc[i][j] + bias[n0 + tn * 4 + j];
            po[j] = fmaxf(v, 0.f);
        }
        *(float4*)(C + (size_t)m * NN + n0 + tn * 4) = o;
    }
}

// ---------------- final classifier layer 2 (chunked) ----------------
__global__ void classifier2(const float* __restrict__ T, const float* __restrict__ w2,
                            const float* __restrict__ b2, float* __restrict__ out, int eoff)
{
    int w = (blockIdx.x * 256 + threadIdx.x) >> 6;
    int lane = threadIdx.x & 63;
    if (w >= CH) return;
    float2 tv = *(const float2*)(T + (size_t)w * 128 + lane * 2);
    float2 wv = *(const float2*)(w2 + lane * 2);
    float r = tv.x * wv.x + tv.y * wv.y;
    #pragma unroll
    for (int o = 32; o > 0; o >>= 1) r += __shfl_down(r, o, 64);
    if (lane == 0) out[eoff + w] = sigmoidf_(r + b2[0]);
}

// =======================================================================================
extern "C" void kernel_launch(void* const* d_in, const int* in_sizes, int n_in,
                              void* d_out, int out_size, void* d_ws, size_t ws_size,
                              hipStream_t stream)
{
    const float* x     = (const float*)d_in[0];
    const float* ge    = (const float*)d_in[1];
    const int*   ei    = (const int*)d_in[2];
    const int*   batch = (const int*)d_in[4];
    const int*   he    = (const int*)d_in[5];
    const float* hw_w1 = (const float*)d_in[6];
    const float* hw_b1 = (const float*)d_in[7];
    const float* hw_w2 = (const float*)d_in[8];
    const float* hw_b2 = (const float*)d_in[9];
    const float* c1_w  = (const float*)d_in[10];
    const float* c1_b  = (const float*)d_in[11];
    const float* c2_w  = (const float*)d_in[12];
    const float* c2_b  = (const float*)d_in[13];
    const float* g_w1  = (const float*)d_in[14];
    const float* g_b1  = (const float*)d_in[15];
    const float* g_w2  = (const float*)d_in[16];
    const float* g_b2  = (const float*)d_in[17];
    const float* cl_w1 = (const float*)d_in[18];
    const float* cl_b1 = (const float*)d_in[19];
    const float* cl_w2 = (const float*)d_in[20];
    const float* cl_b2 = (const float*)d_in[21];
    const float* attn  = (const float*)d_in[22];
    float* out = (float*)d_out;

    char* ws = (char*)d_ws;
    size_t off = 0;
    auto alloc = [&](size_t nb) -> void* {
        off = (off + 255) & ~(size_t)255;
        void* p = ws + off;
        off += nb;
        return p;
    };
    // small arrays (~9.5 MB)
    float* node_w = (float*)alloc((size_t)NODES * 4);
    float* D      = (float*)alloc((size_t)EDGES * 4);   // becomes Dinv in place
    int*   Bcnt   = (int*)  alloc((size_t)NODES * 4);
    float* Binv   = (float*)alloc((size_t)NODES * 4);
    int*   rowCnt = (int*)  alloc((size_t)EDGES * 4);
    int*   colOff = (int*)  alloc((size_t)(NODES + 1) * 4);
    int*   rowOff = (int*)  alloc((size_t)(EDGES + 1) * 4);
    int*   colCur = (int*)  alloc((size_t)NODES * 4);
    int*   rowCur = (int*)  alloc((size_t)EDGES * 4);
    int*   colList= (int*)  alloc((size_t)NNZ_ * 4);
    int*   rowList= (int*)  alloc((size_t)NNZ_ * 4);
    int*   partA  = (int*)  alloc(1024 * 4);
    int*   partB  = (int*)  alloc(1024 * 4);
    // big buffers (~172 MB total)
    float* bufAgg = (float*)alloc((size_t)NODES * 256 * 4);   // agg1 -> agg2 -> Tc (CH*128*4, same size)
    float* bufOe1 = (float*)alloc((size_t)NODES * 256 * 4);   // oe1  -> xl2c (CH*128*4, same size)
    float* oe2    = (float*)alloc((size_t)NODES * 128 * 4);
    __hip_bfloat16* sij = (__hip_bfloat16*)alloc((size_t)EDGES * 128 * 2);
    float* xlc    = (float*)alloc((size_t)CH * 512 * 4);

    float* agg  = bufAgg;        // [NODES,256]
    float* Tc   = bufAgg;        // [CH,128] chunk (reuse after agg2 consumed)
    float* oe1  = bufOe1;        // [NODES,256]
    float* xl2c = bufOe1;        // [CH,128] chunk (reuse after oe1 consumed)

    hipMemsetAsync(D, 0, (size_t)EDGES * 4, stream);
    hipMemsetAsync(Bcnt, 0, (size_t)NODES * 4, stream);
    hipMemsetAsync(rowCnt, 0, (size_t)EDGES * 4, stream);
    hipMemsetAsync(colCur, 0, (size_t)NODES * 4, stream);
    hipMemsetAsync(rowCur, 0, (size_t)EDGES * 4, stream);

    hyperweight_k<<<NODES / 8, 128, 0, stream>>>(x, ge, batch, hw_w1, hw_b1, hw_w2, hw_b2, node_w);
    incidence_pass<<<NNZ_ / 256, 256, 0, stream>>>(he, node_w, D, Bcnt, rowCnt);
    dinv_k<<<EDGES / 256, 256, 0, stream>>>(D);
    binv_k<<<(NODES + 255) / 256, 256, 0, stream>>>(Bcnt, Binv);

    const int ncN = (NODES + 1023) / 1024;
    const int ncE = (EDGES + 1023) / 1024;
    reduce_chunks<<<ncN, 1024, 0, stream>>>(Bcnt, partA, NODES);
    scan_sums<<<1, 1024, 0, stream>>>(partA, ncN);
    scan_chunks<<<ncN, 1024, 0, stream>>>(Bcnt, partA, colOff, NODES);
    reduce_chunks<<<ncE, 1024, 0, stream>>>(rowCnt, partB, EDGES);
    scan_sums<<<1, 1024, 0, stream>>>(partB, ncE);
    scan_chunks<<<ncE, 1024, 0, stream>>>(rowCnt, partB, rowOff, EDGES);
    scatter_pass<<<NNZ_ / 256, 256, 0, stream>>>(he, colOff, rowOff, colCur, rowCur, colList, rowList);

    // conv1 (linear-commuted): oe1 = Binv ⊙ (agg1 @ c1_w)   [NODES,256]
    col_gather_x<<<NODES, 256, 0, stream>>>(x, ei, colOff, colList, agg);
    gemm_node<256, 256><<<dim3(NODES / 64, 4), 256, 0, stream>>>(agg, c1_w, Binv, oe1);

    // conv2: agg2 = sum of er (recomputed on the fly), oe2 = Binv ⊙ (agg2 @ c2_w)  [NODES,128]
    col_gather_er<<<NODES, 256, 0, stream>>>(oe1, D, c1_b, colOff, colList, rowOff, rowList, agg);
    gemm_node<256, 128><<<dim3(NODES / 64, 2), 256, 0, stream>>>(agg, c2_w, Binv, oe2);

    // sij[e] = sigmoid(Dinv[e] * rowsum(oe2) + c2_b)   [EDGES,128] bf16
    sij_k<<<EDGES / 4, 256, 0, stream>>>(oe2, rowOff, rowList, D, c2_b, sij);

    // per-edge tail, chunked: generator MLP + classifier
    for (int c = 0; c < EDGES / CH; ++c) {
        int eoff = c * CH;
        gemm_edge<384, EGEN, 512><<<dim3(CH / 64, 8), 256, 0, stream>>>(
            nullptr, g_w1, g_b1, xlc, ei, batch, x, ge, nullptr, nullptr, eoff);
        gemm_edge<512, EDIR, 128><<<dim3(CH / 64, 2), 256, 0, stream>>>(
            xlc, g_w2, g_b2, xl2c, nullptr, nullptr, nullptr, nullptr, nullptr, nullptr, eoff);
        gemm_edge<256, ECLS, 128><<<dim3(CH / 64, 2), 256, 0, stream>>>(
            xl2c, cl_w1, cl_b1, Tc, ei, batch, nullptr, ge, sij, attn, eoff);
        classifier2<<<CH / 4, 256, 0, stream>>>(Tc, cl_w2, cl_b2, out, eoff);
    }
}

// Round 6
// 1503.747 us; speedup vs baseline: 2.3984x; 2.3984x over previous
//
#include <hip/hip_runtime.h>
#include <hip/hip_bf16.h>

#define NODES  16000
#define FDIM   128
#define EDGES  256000
#define NNZ_   512000
#define CH     64000     // per-edge chunk size (4 chunks)

typedef __attribute__((ext_vector_type(8))) short bf16x8;
typedef __attribute__((ext_vector_type(4))) float f32x4;

__device__ __forceinline__ float sigmoidf_(float z) { return 1.f / (1.f + __expf(-z)); }

// ---------------- HyperWeight: node_w[n] = sigmoid(relu([x|proto]@W1+b1)@W2+b2) -------------
__global__ __launch_bounds__(128) void hyperweight_k(
    const float* __restrict__ x, const float* __restrict__ ge, const int* __restrict__ batch,
    const float* __restrict__ w1, const float* __restrict__ b1,
    const float* __restrict__ w2, const float* __restrict__ b2, float* __restrict__ node_w)
{
    __shared__ float a[8][256];
    __shared__ float red[128];
    const int t = threadIdx.x;
    const int nb = blockIdx.x * 8;
    for (int u = 0; u < 8; ++u) {
        int n = nb + u;
        a[u][t]       = x[(size_t)n * FDIM + t];
        a[u][128 + t] = ge[(size_t)batch[n] * FDIM + t];
    }
    __syncthreads();
    float acc[8] = {0,0,0,0,0,0,0,0};
    for (int k = 0; k < 256; ++k) {
        float wv = w1[k * 128 + t];
        #pragma unroll
        for (int u = 0; u < 8; ++u) acc[u] += a[u][k] * wv;
    }
    const float wv2 = w2[t];
    for (int u = 0; u < 8; ++u) {
        float h = fmaxf(acc[u] + b1[t], 0.f);
        red[t] = h * wv2;
        __syncthreads();
        for (int s2 = 64; s2 > 0; s2 >>= 1) {
            if (t < s2) red[t] += red[t + s2];
            __syncthreads();
        }
        if (t == 0) node_w[nb + u] = sigmoidf_(red[0] + b2[0]);
        __syncthreads();
    }
}

// ---------------- incidence pass: D, Bcnt, rowCnt ----------------
__global__ void incidence_pass(const int* __restrict__ he, const float* __restrict__ node_w,
                               float* __restrict__ D, int* __restrict__ Bcnt, int* __restrict__ rowCnt)
{
    int i = blockIdx.x * 256 + threadIdx.x;
    if (i >= NNZ_) return;
    int hr = he[i];
    int hc = he[NNZ_ + i];
    int hc2 = he[NNZ_ + hc];              // repo quirk: w = node_w[hcol[hcol[i]]]
    atomicAdd(&D[hr], node_w[hc2]);
    atomicAdd(&Bcnt[hc], 1);
    atomicAdd(&rowCnt[hr], 1);
}

__global__ void dinv_k(float* __restrict__ D) {
    int e = blockIdx.x * 256 + threadIdx.x;
    if (e >= EDGES) return;
    float d = D[e];
    D[e] = (d != 0.f) ? 1.f / d : 0.f;
}
__global__ void binv_k(const int* __restrict__ Bcnt, float* __restrict__ Binv) {
    int n = blockIdx.x * 256 + threadIdx.x;
    if (n >= NODES) return;
    int c = Bcnt[n];
    Binv[n] = c ? 1.f / (float)c : 0.f;
}

// ---------------- exclusive scan (3-kernel) ----------------
__global__ __launch_bounds__(1024) void reduce_chunks(const int* __restrict__ in, int* __restrict__ part, int n) {
    __shared__ int s[1024];
    int t = threadIdx.x, g = blockIdx.x * 1024 + t;
    s[t] = (g < n) ? in[g] : 0;
    __syncthreads();
    for (int d = 512; d > 0; d >>= 1) {
        if (t < d) s[t] += s[t + d];
        __syncthreads();
    }
    if (t == 0) part[blockIdx.x] = s[0];
}
__global__ __launch_bounds__(1024) void scan_sums(int* __restrict__ part, int nc) {
    __shared__ int s[1024];
    int t = threadIdx.x;
    int v = (t < nc) ? part[t] : 0;
    s[t] = v;
    __syncthreads();
    for (int d = 1; d < 1024; d <<= 1) {
        int tv = (t >= d) ? s[t - d] : 0;
        __syncthreads();
        s[t] += tv;
        __syncthreads();
    }
    if (t < nc) part[t] = s[t] - v;     // exclusive
}
__global__ __launch_bounds__(1024) void scan_chunks(const int* __restrict__ in, const int* __restrict__ part,
                                                    int* __restrict__ out, int n) {
    __shared__ int s[1024];
    int t = threadIdx.x, g = blockIdx.x * 1024 + t;
    int v = (g < n) ? in[g] : 0;
    s[t] = v;
    __syncthreads();
    for (int d = 1; d < 1024; d <<= 1) {
        int tv = (t >= d) ? s[t - d] : 0;
        __syncthreads();
        s[t] += tv;
        __syncthreads();
    }
    int excl = s[t] - v + part[blockIdx.x];
    if (g < n) out[g] = excl;
    if (g == n - 1) out[n] = excl + v;
}

// ---------------- scatter into CSR lists ----------------
__global__ void scatter_pass(const int* __restrict__ he, const int* __restrict__ colOff, const int* __restrict__ rowOff,
                             int* __restrict__ colCur, int* __restrict__ rowCur,
                             int* __restrict__ colList, int* __restrict__ rowList)
{
    int i = blockIdx.x * 256 + threadIdx.x;
    if (i >= NNZ_) return;
    int hr = he[i];
    int hc = he[NNZ_ + i];
    int p = colOff[hc] + atomicAdd(&colCur[hc], 1);
    colList[p] = hr;
    int q = rowOff[hr] + atomicAdd(&rowCur[hr], 1);
    rowList[q] = hc;
}

// ---------------- fp32 -> bf16 conversion helpers ----------------
__global__ void conv_bf16(const float* __restrict__ in, __hip_bfloat16* __restrict__ out, int n) {
    int i = blockIdx.x * 256 + threadIdx.x;
    if (i < n) out[i] = __float2bfloat16(in[i]);
}
// in [K][N] fp32 -> out [N][K] bf16
__global__ void transpose_bf16(const float* __restrict__ in, __hip_bfloat16* __restrict__ out, int K, int N) {
    int i = blockIdx.x * 256 + threadIdx.x;
    if (i >= K * N) return;
    int n = i / K, k = i - n * K;
    out[i] = __float2bfloat16(in[k * N + n]);
}

// ---------------- agg1[n,256] = sum over edges r in col(n) of [x[ei0[r]] | x[ei1[r]]] ------
__global__ __launch_bounds__(256) void col_gather_x(
    const float* __restrict__ x, const int* __restrict__ ei,
    const int* __restrict__ colOff, const int* __restrict__ colList, float* __restrict__ agg)
{
    int n = blockIdx.x;
    int t = threadIdx.x;
    int base = (t < FDIM) ? 0 : EDGES;
    int f = t & (FDIM - 1);
    int s = colOff[n], e = colOff[n + 1];
    float acc = 0.f;
    for (int j = s; j < e; ++j) {
        int r = colList[j];
        int id = ei[base + r];
        acc += x[(size_t)id * FDIM + f];
    }
    agg[(size_t)n * 256 + t] = acc;
}

// ---------------- agg2[n,256] = sum over r in col(n) of er[r], er recomputed on the fly ----
__global__ __launch_bounds__(256) void col_gather_er(
    const __hip_bfloat16* __restrict__ oe1, const float* __restrict__ Dinv, const float* __restrict__ c1b,
    const int* __restrict__ colOff, const int* __restrict__ colList,
    const int* __restrict__ rowOff, const int* __restrict__ rowList, float* __restrict__ agg)
{
    int n = blockIdx.x;
    int t = threadIdx.x;
    int s = colOff[n], e = colOff[n + 1];
    float b = c1b[t];
    float acc = 0.f;
    for (int j = s; j < e; ++j) {
        int r = colList[j];
        int rs = rowOff[r], re = rowOff[r + 1];
        float v = 0.f;
        for (int q = rs; q < re; ++q)
            v += __bfloat162float(oe1[(size_t)rowList[q] * 256 + t]);
        acc += sigmoidf_(Dinv[r] * v + b);
    }
    agg[(size_t)n * 256 + t] = acc;
}

// ---------------- node-rows GEMM: C[m,n] = rowscale[m] * (A @ B)[m,n] ----------------
template<int K, int NN, bool OB16>
__global__ __launch_bounds__(256) void gemm_node(
    const float* __restrict__ A, const float* __restrict__ B,
    const float* __restrict__ rowscale, void* __restrict__ C)
{
    __shared__ float As[16][68];
    __shared__ float Bs[16][68];
    const int tid = threadIdx.x;
    const int m0 = blockIdx.x * 64, n0 = blockIdx.y * 64;
    const int la_k = tid & 15, la_m = tid >> 4;
    const int lb_n = tid & 63, lb_k = tid >> 6;
    const int tn = tid & 15, tm = tid >> 4;
    float acc[4][4] = {};
    for (int k0 = 0; k0 < K; k0 += 16) {
        #pragma unroll
        for (int r = 0; r < 4; ++r)
            As[la_k][la_m + 16 * r] = A[(size_t)(m0 + la_m + 16 * r) * K + k0 + la_k];
        #pragma unroll
        for (int r = 0; r < 4; ++r)
            Bs[lb_k + 4 * r][lb_n] = B[(size_t)(k0 + lb_k + 4 * r) * NN + n0 + lb_n];
        __syncthreads();
        #pragma unroll
        for (int kk = 0; kk < 16; ++kk) {
            float4 av = *(const float4*)&As[kk][tm * 4];
            float4 bv = *(const float4*)&Bs[kk][tn * 4];
            float am[4] = {av.x, av.y, av.z, av.w};
            float bn[4] = {bv.x, bv.y, bv.z, bv.w};
            #pragma unroll
            for (int i = 0; i < 4; ++i)
                #pragma unroll
                for (int j = 0; j < 4; ++j)
                    acc[i][j] += am[i] * bn[j];
        }
        __syncthreads();
    }
    #pragma unroll
    for (int i = 0; i < 4; ++i) {
        int m = m0 + tm * 4 + i;
        float rs = rowscale[m];
        if constexpr (OB16) {
            __hip_bfloat16* Cp = (__hip_bfloat16*)C + (size_t)m * NN + n0 + tn * 4;
            #pragma unroll
            for (int j = 0; j < 4; ++j) Cp[j] = __float2bfloat16(rs * acc[i][j]);
        } else {
            float4 o = make_float4(rs * acc[i][0], rs * acc[i][1], rs * acc[i][2], rs * acc[i][3]);
            *(float4*)((float*)C + (size_t)m * NN + n0 + tn * 4) = o;
        }
    }
}

// ---------------- sij[e,128] (bf16) = sigmoid(Dinv[e]*rowsum(oe2) + c2_b) ----------------
__global__ void sij_k(const float* __restrict__ oe2, const int* __restrict__ rowOff,
                      const int* __restrict__ rowList, const float* __restrict__ Dinv,
                      const float* __restrict__ bias, __hip_bfloat16* __restrict__ sij)
{
    int w = (blockIdx.x * 256 + threadIdx.x) >> 6;
    int lane = threadIdx.x & 63;
    if (w >= EDGES) return;
    int s = rowOff[w], t = rowOff[w + 1];
    float2 acc = make_float2(0.f, 0.f);
    for (int j = s; j < t; ++j) {
        int n = rowList[j];
        float2 q = *(const float2*)(oe2 + (size_t)n * 128 + lane * 2);
        acc.x += q.x; acc.y += q.y;
    }
    float dv = Dinv[w];
    float2 b = *(const float2*)(bias + lane * 2);
    __hip_bfloat162 h;
    h.x = __float2bfloat16(sigmoidf_(dv * acc.x + b.x));
    h.y = __float2bfloat16(sigmoidf_(dv * acc.y + b.y));
    *(__hip_bfloat162*)(sij + (size_t)w * 128 + lane * 2) = h;
}

// ---------------- bf16 MFMA edge GEMM, 64x64 tile, fused gathers ----------------
enum { EGEN = 0, EDIR = 1, ECLS = 2 };

__device__ __forceinline__ unsigned bf2_combine(unsigned a, unsigned b, float a0, float a1) {
    float alo = __uint_as_float(a << 16), ahi = __uint_as_float(a & 0xffff0000u);
    float blo = __uint_as_float(b << 16), bhi = __uint_as_float(b & 0xffff0000u);
    __hip_bfloat162 h;
    h.x = __float2bfloat16(a0 * alo + a1 * blo);
    h.y = __float2bfloat16(a0 * ahi + a1 * bhi);
    return *(unsigned*)&h;
}

template<int K, int AMODE, int NN>
__global__ __launch_bounds__(256) void gemm_edge_mfma(
    const __hip_bfloat16* __restrict__ Asrc,   // EDIR: xl [CH][K]; ECLS: xl2 [CH][128]
    const __hip_bfloat16* __restrict__ Bt,     // weights transposed [NN][K] bf16
    const float* __restrict__ bias,
    __hip_bfloat16* __restrict__ C,            // [CH][NN] bf16
    const int* __restrict__ ei, const int* __restrict__ batch,
    const __hip_bfloat16* __restrict__ xb, const __hip_bfloat16* __restrict__ geb,
    const __hip_bfloat16* __restrict__ sij, const float* __restrict__ attn, int eoff)
{
    __shared__ __align__(16) __hip_bfloat16 As[64][40];
    __shared__ __align__(16) __hip_bfloat16 Bs[64][40];   // Bs[n][k]
    const int tid = threadIdx.x;
    const int m0 = blockIdx.x * 64, n0 = blockIdx.y * 64;
    const int wave = tid >> 6, lane = tid & 63;
    const int wr = wave >> 1, wc = wave & 1;
    const int srow = tid >> 2, kseg = (tid & 3) * 8;

    int rA = 0, rB = 0, rG = 0;
    if constexpr (AMODE == EGEN) {
        int eg = eoff + m0 + srow;
        int a = ei[eg];
        rA = a * FDIM;
        rB = ei[EDGES + eg] * FDIM;
        rG = batch[a] * FDIM;
    }
    if constexpr (AMODE == ECLS) {
        rG = batch[ei[eoff + m0 + srow]] * FDIM;
    }
    float a0 = 0.f, a1 = 0.f;
    if constexpr (AMODE == ECLS) { a0 = attn[0]; a1 = attn[1]; }

    f32x4 acc[2][2] = {};
    for (int k0 = 0; k0 < K; k0 += 32) {
        int kg = k0 + kseg;
        // ---- stage A tile (64 rows x 32 k) ----
        uint4 av;
        if constexpr (AMODE == EGEN) {
            const __hip_bfloat16* src;
            int kk;
            if (kg < FDIM)            { src = xb + rA;  kk = kg; }
            else if (kg < 2 * FDIM)   { src = xb + rB;  kk = kg - FDIM; }
            else                      { src = geb + rG; kk = kg - 2 * FDIM; }
            av = *(const uint4*)(src + kk);
        } else if constexpr (AMODE == ECLS) {
            if (kg < FDIM) {
                uint4 u = *(const uint4*)(Asrc + (size_t)(m0 + srow) * FDIM + kg);
                uint4 s = *(const uint4*)(sij + (size_t)(eoff + m0 + srow) * FDIM + kg);
                av.x = bf2_combine(u.x, s.x, a0, a1);
                av.y = bf2_combine(u.y, s.y, a0, a1);
                av.z = bf2_combine(u.z, s.z, a0, a1);
                av.w = bf2_combine(u.w, s.w, a0, a1);
            } else {
                av = *(const uint4*)(geb + rG + kg - FDIM);
            }
        } else {
            av = *(const uint4*)(Asrc + (size_t)(m0 + srow) * K + kg);
        }
        *(uint4*)&As[srow][kseg] = av;
        // ---- stage B tile (64 cols x 32 k) ----
        uint4 bv = *(const uint4*)(Bt + (size_t)(n0 + srow) * K + kg);
        *(uint4*)&Bs[srow][kseg] = bv;
        __syncthreads();
        // ---- fragments + MFMA ----
        const int fr = lane & 15, krow = (lane >> 4) * 8;
        bf16x8 af0 = *(const bf16x8*)&As[wr * 32 + fr][krow];
        bf16x8 af1 = *(const bf16x8*)&As[wr * 32 + 16 + fr][krow];
        bf16x8 bf0 = *(const bf16x8*)&Bs[wc * 32 + fr][krow];
        bf16x8 bf1 = *(const bf16x8*)&Bs[wc * 32 + 16 + fr][krow];
        acc[0][0] = __builtin_amdgcn_mfma_f32_16x16x32_bf16(af0, bf0, acc[0][0], 0, 0, 0);
        acc[0][1] = __builtin_amdgcn_mfma_f32_16x16x32_bf16(af0, bf1, acc[0][1], 0, 0, 0);
        acc[1][0] = __builtin_amdgcn_mfma_f32_16x16x32_bf16(af1, bf0, acc[1][0], 0, 0, 0);
        acc[1][1] = __builtin_amdgcn_mfma_f32_16x16x32_bf16(af1, bf1, acc[1][1], 0, 0, 0);
        __syncthreads();
    }
    // ---- epilogue: bias + relu, bf16 store ----
    const int fr = lane & 15, rq = lane >> 4;
    #pragma unroll
    for (int i = 0; i < 2; ++i) {
        #pragma unroll
        for (int j = 0; j < 2; ++j) {
            int col = n0 + wc * 32 + j * 16 + fr;
            float bcol = bias[col];
            #pragma unroll
            for (int r = 0; r < 4; ++r) {
                int row = m0 + wr * 32 + i * 16 + rq * 4 + r;
                float v = acc[i][j][r] + bcol;
                v = fmaxf(v, 0.f);
                C[(size_t)row * NN + col] = __float2bfloat16(v);
            }
        }
    }
}

// ---------------- final classifier layer 2 (chunked, bf16 T) ----------------
__global__ void classifier2b(const __hip_bfloat16* __restrict__ T, const float* __restrict__ w2,
                             const float* __restrict__ b2, float* __restrict__ out, int eoff)
{
    int w = (blockIdx.x * 256 + threadIdx.x) >> 6;
    int lane = threadIdx.x & 63;
    if (w >= CH) return;
    unsigned tv = *(const unsigned*)(T + (size_t)w * 128 + lane * 2);
    float2 wv = *(const float2*)(w2 + lane * 2);
    float lo = __uint_as_float(tv << 16), hi = __uint_as_float(tv & 0xffff0000u);
    float r = lo * wv.x + hi * wv.y;
    #pragma unroll
    for (int o = 32; o > 0; o >>= 1) r += __shfl_down(r, o, 64);
    if (lane == 0) out[eoff + w] = sigmoidf_(r + b2[0]);
}

// =======================================================================================
extern "C" void kernel_launch(void* const* d_in, const int* in_sizes, int n_in,
                              void* d_out, int out_size, void* d_ws, size_t ws_size,
                              hipStream_t stream)
{
    const float* x     = (const float*)d_in[0];
    const float* ge    = (const float*)d_in[1];
    const int*   ei    = (const int*)d_in[2];
    const int*   batch = (const int*)d_in[4];
    const int*   he    = (const int*)d_in[5];
    const float* hw_w1 = (const float*)d_in[6];
    const float* hw_b1 = (const float*)d_in[7];
    const float* hw_w2 = (const float*)d_in[8];
    const float* hw_b2 = (const float*)d_in[9];
    const float* c1_w  = (const float*)d_in[10];
    const float* c1_b  = (const float*)d_in[11];
    const float* c2_w  = (const float*)d_in[12];
    const float* c2_b  = (const float*)d_in[13];
    const float* g_w1  = (const float*)d_in[14];
    const float* g_b1  = (const float*)d_in[15];
    const float* g_w2  = (const float*)d_in[16];
    const float* g_b2  = (const float*)d_in[17];
    const float* cl_w1 = (const float*)d_in[18];
    const float* cl_b1 = (const float*)d_in[19];
    const float* cl_w2 = (const float*)d_in[20];
    const float* cl_b2 = (const float*)d_in[21];
    const float* attn  = (const float*)d_in[22];
    float* out = (float*)d_out;

    char* ws = (char*)d_ws;
    size_t off = 0;
    auto alloc = [&](size_t nb) -> void* {
        off = (off + 255) & ~(size_t)255;
        void* p = ws + off;
        off += nb;
        return p;
    };
    // small arrays (~9.5 MB)
    float* node_w = (float*)alloc((size_t)NODES * 4);
    float* D      = (float*)alloc((size_t)EDGES * 4);   // becomes Dinv in place
    int*   Bcnt   = (int*)  alloc((size_t)NODES * 4);
    float* Binv   = (float*)alloc((size_t)NODES * 4);
    int*   rowCnt = (int*)  alloc((size_t)EDGES * 4);
    int*   colOff = (int*)  alloc((size_t)(NODES + 1) * 4);
    int*   rowOff = (int*)  alloc((size_t)(EDGES + 1) * 4);
    int*   colCur = (int*)  alloc((size_t)NODES * 4);
    int*   rowCur = (int*)  alloc((size_t)EDGES * 4);
    int*   colList= (int*)  alloc((size_t)NNZ_ * 4);
    int*   rowList= (int*)  alloc((size_t)NNZ_ * 4);
    int*   partA  = (int*)  alloc(1024 * 4);
    int*   partB  = (int*)  alloc(1024 * 4);
    // bf16 conversions (~5 MB)
    __hip_bfloat16* xb    = (__hip_bfloat16*)alloc((size_t)NODES * FDIM * 2);
    __hip_bfloat16* geb   = (__hip_bfloat16*)alloc((size_t)512 * FDIM * 2);
    __hip_bfloat16* gw1t  = (__hip_bfloat16*)alloc((size_t)512 * 384 * 2);
    __hip_bfloat16* gw2t  = (__hip_bfloat16*)alloc((size_t)128 * 512 * 2);
    __hip_bfloat16* clw1t = (__hip_bfloat16*)alloc((size_t)128 * 256 * 2);
    // big buffers (~172 MB)
    float* agg    = (float*)alloc((size_t)NODES * 256 * 4);   // agg1/agg2; later Tc bf16 [CH][128]
    void*  bufOX  = alloc((size_t)NODES * 256 * 4);           // oe1 bf16; later xl2c bf16 [CH][128]
    float* oe2    = (float*)alloc((size_t)NODES * 128 * 4);
    __hip_bfloat16* sij = (__hip_bfloat16*)alloc((size_t)EDGES * 128 * 2);
    __hip_bfloat16* xlc = (__hip_bfloat16*)alloc((size_t)CH * 512 * 2);

    __hip_bfloat16* oe1b = (__hip_bfloat16*)bufOX;   // [NODES][256] bf16
    __hip_bfloat16* xl2c = (__hip_bfloat16*)bufOX;   // [CH][128] bf16 (after oe1 consumed)
    __hip_bfloat16* Tc   = (__hip_bfloat16*)agg;     // [CH][128] bf16 (after agg consumed)

    hipMemsetAsync(D, 0, (size_t)EDGES * 4, stream);
    hipMemsetAsync(Bcnt, 0, (size_t)NODES * 4, stream);
    hipMemsetAsync(rowCnt, 0, (size_t)EDGES * 4, stream);
    hipMemsetAsync(colCur, 0, (size_t)NODES * 4, stream);
    hipMemsetAsync(rowCur, 0, (size_t)EDGES * 4, stream);

    hyperweight_k<<<NODES / 8, 128, 0, stream>>>(x, ge, batch, hw_w1, hw_b1, hw_w2, hw_b2, node_w);
    incidence_pass<<<NNZ_ / 256, 256, 0, stream>>>(he, node_w, D, Bcnt, rowCnt);
    dinv_k<<<EDGES / 256, 256, 0, stream>>>(D);
    binv_k<<<(NODES + 255) / 256, 256, 0, stream>>>(Bcnt, Binv);

    const int ncN = (NODES + 1023) / 1024;
    const int ncE = (EDGES + 1023) / 1024;
    reduce_chunks<<<ncN, 1024, 0, stream>>>(Bcnt, partA, NODES);
    scan_sums<<<1, 1024, 0, stream>>>(partA, ncN);
    scan_chunks<<<ncN, 1024, 0, stream>>>(Bcnt, partA, colOff, NODES);
    reduce_chunks<<<ncE, 1024, 0, stream>>>(rowCnt, partB, EDGES);
    scan_sums<<<1, 1024, 0, stream>>>(partB, ncE);
    scan_chunks<<<ncE, 1024, 0, stream>>>(rowCnt, partB, rowOff, EDGES);
    scatter_pass<<<NNZ_ / 256, 256, 0, stream>>>(he, colOff, rowOff, colCur, rowCur, colList, rowList);

    // bf16 conversions / weight transposes
    conv_bf16<<<(NODES * FDIM + 255) / 256, 256, 0, stream>>>(x, xb, NODES * FDIM);
    conv_bf16<<<(512 * FDIM + 255) / 256, 256, 0, stream>>>(ge, geb, 512 * FDIM);
    transpose_bf16<<<(384 * 512 + 255) / 256, 256, 0, stream>>>(g_w1, gw1t, 384, 512);
    transpose_bf16<<<(512 * 128 + 255) / 256, 256, 0, stream>>>(g_w2, gw2t, 512, 128);
    transpose_bf16<<<(256 * 128 + 255) / 256, 256, 0, stream>>>(cl_w1, clw1t, 256, 128);

    // conv1 (linear-commuted): oe1 = Binv ⊙ (agg1 @ c1_w)   [NODES,256] bf16
    col_gather_x<<<NODES, 256, 0, stream>>>(x, ei, colOff, colList, agg);
    gemm_node<256, 256, true><<<dim3(NODES / 64, 4), 256, 0, stream>>>(agg, c1_w, Binv, oe1b);

    // conv2: agg2 = sum of er (recomputed), oe2 = Binv ⊙ (agg2 @ c2_w)  [NODES,128] fp32
    col_gather_er<<<NODES, 256, 0, stream>>>(oe1b, D, c1_b, colOff, colList, rowOff, rowList, agg);
    gemm_node<256, 128, false><<<dim3(NODES / 64, 2), 256, 0, stream>>>(agg, c2_w, Binv, oe2);

    // sij[e] = sigmoid(Dinv[e] * rowsum(oe2) + c2_b)   [EDGES,128] bf16
    sij_k<<<EDGES / 4, 256, 0, stream>>>(oe2, rowOff, rowList, D, c2_b, sij);

    // per-edge tail, chunked, all bf16 MFMA
    for (int c = 0; c < EDGES / CH; ++c) {
        int eoff = c * CH;
        gemm_edge_mfma<384, EGEN, 512><<<dim3(CH / 64, 8), 256, 0, stream>>>(
            nullptr, gw1t, g_b1, xlc, ei, batch, xb, geb, nullptr, nullptr, eoff);
        gemm_edge_mfma<512, EDIR, 128><<<dim3(CH / 64, 2), 256, 0, stream>>>(
            xlc, gw2t, g_b2, xl2c, nullptr, nullptr, nullptr, nullptr, nullptr, nullptr, eoff);
        gemm_edge_mfma<256, ECLS, 128><<<dim3(CH / 64, 2), 256, 0, stream>>>(
            xl2c, clw1t, cl_b1, Tc, ei, batch, nullptr, geb, sij, attn, eoff);
        classifier2b<<<CH / 4, 256, 0, stream>>>(Tc, cl_w2, cl_b2, out, eoff);
    }
}

// Round 7
// 1080.294 us; speedup vs baseline: 3.3385x; 1.3920x over previous
//
#include <hip/hip_runtime.h>
#include <hip/hip_bf16.h>

#define NODES  16000
#define FDIM   128
#define EDGES  256000
#define NNZ_   512000
#define CH     64000     // per-edge chunk size (4 chunks)

typedef __attribute__((ext_vector_type(8))) short bf16x8;
typedef __attribute__((ext_vector_type(4))) float f32x4;

__device__ __forceinline__ float sigmoidf_(float z) { return 1.f / (1.f + __expf(-z)); }
__device__ __forceinline__ float bflo(unsigned u) { return __uint_as_float(u << 16); }
__device__ __forceinline__ float bfhi(unsigned u) { return __uint_as_float(u & 0xffff0000u); }

// ---------------- HyperWeight: node_w[n] = sigmoid(relu([x|proto]@W1+b1)@W2+b2) -------------
__global__ __launch_bounds__(128) void hyperweight_k(
    const float* __restrict__ x, const float* __restrict__ ge, const int* __restrict__ batch,
    const float* __restrict__ w1, const float* __restrict__ b1,
    const float* __restrict__ w2, const float* __restrict__ b2, float* __restrict__ node_w)
{
    __shared__ float a[8][256];
    __shared__ float red[128];
    const int t = threadIdx.x;
    const int nb = blockIdx.x * 8;
    for (int u = 0; u < 8; ++u) {
        int n = nb + u;
        a[u][t]       = x[(size_t)n * FDIM + t];
        a[u][128 + t] = ge[(size_t)batch[n] * FDIM + t];
    }
    __syncthreads();
    float acc[8] = {0,0,0,0,0,0,0,0};
    for (int k = 0; k < 256; ++k) {
        float wv = w1[k * 128 + t];
        #pragma unroll
        for (int u = 0; u < 8; ++u) acc[u] += a[u][k] * wv;
    }
    const float wv2 = w2[t];
    for (int u = 0; u < 8; ++u) {
        float h = fmaxf(acc[u] + b1[t], 0.f);
        red[t] = h * wv2;
        __syncthreads();
        for (int s2 = 64; s2 > 0; s2 >>= 1) {
            if (t < s2) red[t] += red[t + s2];
            __syncthreads();
        }
        if (t == 0) node_w[nb + u] = sigmoidf_(red[0] + b2[0]);
        __syncthreads();
    }
}

// ---------------- incidence pass: D, Bcnt, rowCnt ----------------
__global__ void incidence_pass(const int* __restrict__ he, const float* __restrict__ node_w,
                               float* __restrict__ D, int* __restrict__ Bcnt, int* __restrict__ rowCnt)
{
    int i = blockIdx.x * 256 + threadIdx.x;
    if (i >= NNZ_) return;
    int hr = he[i];
    int hc = he[NNZ_ + i];
    int hc2 = he[NNZ_ + hc];              // repo quirk: w = node_w[hcol[hcol[i]]]
    atomicAdd(&D[hr], node_w[hc2]);
    atomicAdd(&Bcnt[hc], 1);
    atomicAdd(&rowCnt[hr], 1);
}

__global__ void dinv_k(float* __restrict__ D) {
    int e = blockIdx.x * 256 + threadIdx.x;
    if (e >= EDGES) return;
    float d = D[e];
    D[e] = (d != 0.f) ? 1.f / d : 0.f;
}
__global__ void binv_k(const int* __restrict__ Bcnt, float* __restrict__ Binv) {
    int n = blockIdx.x * 256 + threadIdx.x;
    if (n >= NODES) return;
    int c = Bcnt[n];
    Binv[n] = c ? 1.f / (float)c : 0.f;
}

// ---------------- exclusive scan (3-kernel) ----------------
__global__ __launch_bounds__(1024) void reduce_chunks(const int* __restrict__ in, int* __restrict__ part, int n) {
    __shared__ int s[1024];
    int t = threadIdx.x, g = blockIdx.x * 1024 + t;
    s[t] = (g < n) ? in[g] : 0;
    __syncthreads();
    for (int d = 512; d > 0; d >>= 1) {
        if (t < d) s[t] += s[t + d];
        __syncthreads();
    }
    if (t == 0) part[blockIdx.x] = s[0];
}
__global__ __launch_bounds__(1024) void scan_sums(int* __restrict__ part, int nc) {
    __shared__ int s[1024];
    int t = threadIdx.x;
    int v = (t < nc) ? part[t] : 0;
    s[t] = v;
    __syncthreads();
    for (int d = 1; d < 1024; d <<= 1) {
        int tv = (t >= d) ? s[t - d] : 0;
        __syncthreads();
        s[t] += tv;
        __syncthreads();
    }
    if (t < nc) part[t] = s[t] - v;     // exclusive
}
__global__ __launch_bounds__(1024) void scan_chunks(const int* __restrict__ in, const int* __restrict__ part,
                                                    int* __restrict__ out, int n) {
    __shared__ int s[1024];
    int t = threadIdx.x, g = blockIdx.x * 1024 + t;
    int v = (g < n) ? in[g] : 0;
    s[t] = v;
    __syncthreads();
    for (int d = 1; d < 1024; d <<= 1) {
        int tv = (t >= d) ? s[t - d] : 0;
        __syncthreads();
        s[t] += tv;
        __syncthreads();
    }
    int excl = s[t] - v + part[blockIdx.x];
    if (g < n) out[g] = excl;
    if (g == n - 1) out[n] = excl + v;
}

// ---------------- scatter into CSR lists ----------------
__global__ void scatter_pass(const int* __restrict__ he, const int* __restrict__ colOff, const int* __restrict__ rowOff,
                             int* __restrict__ colCur, int* __restrict__ rowCur,
                             int* __restrict__ colList, int* __restrict__ rowList)
{
    int i = blockIdx.x * 256 + threadIdx.x;
    if (i >= NNZ_) return;
    int hr = he[i];
    int hc = he[NNZ_ + i];
    int p = colOff[hc] + atomicAdd(&colCur[hc], 1);
    colList[p] = hr;
    int q = rowOff[hr] + atomicAdd(&rowCur[hr], 1);
    rowList[q] = hc;
}

// ---------------- fp32 -> bf16 conversion helpers ----------------
__global__ void conv_bf16(const float* __restrict__ in, __hip_bfloat16* __restrict__ out, int n) {
    int i = blockIdx.x * 256 + threadIdx.x;
    if (i < n) out[i] = __float2bfloat16(in[i]);
}
// in [K][N] fp32 -> out [N][K] bf16
__global__ void transpose_bf16(const float* __restrict__ in, __hip_bfloat16* __restrict__ out, int K, int N) {
    int i = blockIdx.x * 256 + threadIdx.x;
    if (i >= K * N) return;
    int n = i / K, k = i - n * K;
    out[i] = __float2bfloat16(in[k * N + n]);
}

// ---------------- agg1[n,256] = sum over edges r in col(n) of [xb[ei0[r]] | xb[ei1[r]]] ----
__global__ __launch_bounds__(128) void col_gather_x(
    const __hip_bfloat16* __restrict__ xb, const int* __restrict__ ei,
    const int* __restrict__ colOff, const int* __restrict__ colList, float* __restrict__ agg)
{
    int n = blockIdx.x;
    int t = threadIdx.x;                    // 128 threads: t<64 -> col half, t>=64 -> row half
    int base = (t < 64) ? 0 : EDGES;
    int f = t & 63;                         // feature-pair index (features 2f, 2f+1)
    const unsigned* x32 = (const unsigned*)xb;
    int s = colOff[n], e = colOff[n + 1];
    float vx = 0.f, vy = 0.f;
    int j = s;
    for (; j + 3 < e; j += 4) {
        int r0 = colList[j], r1 = colList[j + 1], r2 = colList[j + 2], r3 = colList[j + 3];
        unsigned q0 = x32[(size_t)ei[base + r0] * 64 + f];
        unsigned q1 = x32[(size_t)ei[base + r1] * 64 + f];
        unsigned q2 = x32[(size_t)ei[base + r2] * 64 + f];
        unsigned q3 = x32[(size_t)ei[base + r3] * 64 + f];
        vx += bflo(q0) + bflo(q1) + bflo(q2) + bflo(q3);
        vy += bfhi(q0) + bfhi(q1) + bfhi(q2) + bfhi(q3);
    }
    for (; j < e; ++j) {
        unsigned q0 = x32[(size_t)ei[base + colList[j]] * 64 + f];
        vx += bflo(q0); vy += bfhi(q0);
    }
    int ob = (t < 64) ? 0 : 128;
    float2 o = make_float2(vx, vy);
    *(float2*)(agg + (size_t)n * 256 + ob + 2 * f) = o;
}

// ---------------- er[r,256] (bf16) = sigmoid(Dinv[r]*rowsum(oe1) + c1_b) ----------------
__global__ __launch_bounds__(128) void er_k(
    const __hip_bfloat16* __restrict__ oe1, const int* __restrict__ rowOff,
    const int* __restrict__ rowList, const float* __restrict__ Dinv,
    const float* __restrict__ c1b, __hip_bfloat16* __restrict__ er)
{
    int r = blockIdx.x;
    int t = threadIdx.x;                    // 128 threads, 2 features each
    int s = rowOff[r], e = rowOff[r + 1];
    const unsigned* o32 = (const unsigned*)oe1;
    float vx = 0.f, vy = 0.f;
    int j = s;
    for (; j + 1 < e; j += 2) {
        unsigned q0 = o32[(size_t)rowList[j] * 128 + t];
        unsigned q1 = o32[(size_t)rowList[j + 1] * 128 + t];
        vx += bflo(q0) + bflo(q1);
        vy += bfhi(q0) + bfhi(q1);
    }
    if (j < e) {
        unsigned q0 = o32[(size_t)rowList[j] * 128 + t];
        vx += bflo(q0); vy += bfhi(q0);
    }
    float dv = Dinv[r];
    __hip_bfloat162 h;
    h.x = __float2bfloat16(sigmoidf_(dv * vx + c1b[2 * t]));
    h.y = __float2bfloat16(sigmoidf_(dv * vy + c1b[2 * t + 1]));
    *(__hip_bfloat162*)(er + (size_t)r * 256 + 2 * t) = h;
}

// ---------------- agg2[n,256] = sum over r in col(n) of er[r] ----------------
__global__ __launch_bounds__(128) void col_agg_er(
    const __hip_bfloat16* __restrict__ er, const int* __restrict__ colOff,
    const int* __restrict__ colList, float* __restrict__ agg)
{
    int n = blockIdx.x;
    int t = threadIdx.x;                    // 128 threads, 2 features each
    const unsigned* e32 = (const unsigned*)er;
    int s = colOff[n], e = colOff[n + 1];
    float vx = 0.f, vy = 0.f;
    int j = s;
    for (; j + 3 < e; j += 4) {
        unsigned q0 = e32[(size_t)colList[j]     * 128 + t];
        unsigned q1 = e32[(size_t)colList[j + 1] * 128 + t];
        unsigned q2 = e32[(size_t)colList[j + 2] * 128 + t];
        unsigned q3 = e32[(size_t)colList[j + 3] * 128 + t];
        vx += bflo(q0) + bflo(q1) + bflo(q2) + bflo(q3);
        vy += bfhi(q0) + bfhi(q1) + bfhi(q2) + bfhi(q3);
    }
    for (; j < e; ++j) {
        unsigned q0 = e32[(size_t)colList[j] * 128 + t];
        vx += bflo(q0); vy += bfhi(q0);
    }
    float2 o = make_float2(vx, vy);
    *(float2*)(agg + (size_t)n * 256 + 2 * t) = o;
}

// ---------------- node-rows GEMM: C[m,n] = rowscale[m] * (A @ B)[m,n] ----------------
template<int K, int NN, bool OB16>
__global__ __launch_bounds__(256) void gemm_node(
    const float* __restrict__ A, const float* __restrict__ B,
    const float* __restrict__ rowscale, void* __restrict__ C)
{
    __shared__ float As[16][68];
    __shared__ float Bs[16][68];
    const int tid = threadIdx.x;
    const int m0 = blockIdx.x * 64, n0 = blockIdx.y * 64;
    const int la_k = tid & 15, la_m = tid >> 4;
    const int lb_n = tid & 63, lb_k = tid >> 6;
    const int tn = tid & 15, tm = tid >> 4;
    float acc[4][4] = {};
    for (int k0 = 0; k0 < K; k0 += 16) {
        #pragma unroll
        for (int r = 0; r < 4; ++r)
            As[la_k][la_m + 16 * r] = A[(size_t)(m0 + la_m + 16 * r) * K + k0 + la_k];
        #pragma unroll
        for (int r = 0; r < 4; ++r)
            Bs[lb_k + 4 * r][lb_n] = B[(size_t)(k0 + lb_k + 4 * r) * NN + n0 + lb_n];
        __syncthreads();
        #pragma unroll
        for (int kk = 0; kk < 16; ++kk) {
            float4 av = *(const float4*)&As[kk][tm * 4];
            float4 bv = *(const float4*)&Bs[kk][tn * 4];
            float am[4] = {av.x, av.y, av.z, av.w};
            float bn[4] = {bv.x, bv.y, bv.z, bv.w};
            #pragma unroll
            for (int i = 0; i < 4; ++i)
                #pragma unroll
                for (int j = 0; j < 4; ++j)
                    acc[i][j] += am[i] * bn[j];
        }
        __syncthreads();
    }
    #pragma unroll
    for (int i = 0; i < 4; ++i) {
        int m = m0 + tm * 4 + i;
        float rs = rowscale[m];
        if constexpr (OB16) {
            __hip_bfloat16* Cp = (__hip_bfloat16*)C + (size_t)m * NN + n0 + tn * 4;
            #pragma unroll
            for (int j = 0; j < 4; ++j) Cp[j] = __float2bfloat16(rs * acc[i][j]);
        } else {
            float4 o = make_float4(rs * acc[i][0], rs * acc[i][1], rs * acc[i][2], rs * acc[i][3]);
            *(float4*)((float*)C + (size_t)m * NN + n0 + tn * 4) = o;
        }
    }
}

// ---------------- sij[e,128] (bf16) = sigmoid(Dinv[e]*rowsum(oe2) + c2_b) ----------------
__global__ void sij_k(const __hip_bfloat16* __restrict__ oe2, const int* __restrict__ rowOff,
                      const int* __restrict__ rowList, const float* __restrict__ Dinv,
                      const float* __restrict__ bias, __hip_bfloat16* __restrict__ sij)
{
    int w = (blockIdx.x * 256 + threadIdx.x) >> 6;
    int lane = threadIdx.x & 63;
    if (w >= EDGES) return;
    int s = rowOff[w], t = rowOff[w + 1];
    const unsigned* o32 = (const unsigned*)oe2;
    float ax = 0.f, ay = 0.f;
    for (int j = s; j < t; ++j) {
        unsigned q = o32[(size_t)rowList[j] * 64 + lane];
        ax += bflo(q); ay += bfhi(q);
    }
    float dv = Dinv[w];
    float2 b = *(const float2*)(bias + lane * 2);
    __hip_bfloat162 h;
    h.x = __float2bfloat16(sigmoidf_(dv * ax + b.x));
    h.y = __float2bfloat16(sigmoidf_(dv * ay + b.y));
    *(__hip_bfloat162*)(sij + (size_t)w * 128 + lane * 2) = h;
}

// ---------------- bf16 MFMA edge GEMM, 64x64 tile, fused gathers ----------------
enum { EGEN = 0, EDIR = 1, ECLS = 2 };

__device__ __forceinline__ unsigned bf2_combine(unsigned a, unsigned b, float a0, float a1) {
    __hip_bfloat162 h;
    h.x = __float2bfloat16(a0 * bflo(a) + a1 * bflo(b));
    h.y = __float2bfloat16(a0 * bfhi(a) + a1 * bfhi(b));
    return *(unsigned*)&h;
}

template<int K, int AMODE, int NN>
__global__ __launch_bounds__(256) void gemm_edge_mfma(
    const __hip_bfloat16* __restrict__ Asrc,   // EDIR: xl [CH][K]; ECLS: xl2 [CH][128]
    const __hip_bfloat16* __restrict__ Bt,     // weights transposed [NN][K] bf16
    const float* __restrict__ bias,
    __hip_bfloat16* __restrict__ C,            // [CH][NN] bf16
    const int* __restrict__ ei, const int* __restrict__ batch,
    const __hip_bfloat16* __restrict__ xb, const __hip_bfloat16* __restrict__ geb,
    const __hip_bfloat16* __restrict__ sij, const float* __restrict__ attn, int eoff)
{
    __shared__ __align__(16) __hip_bfloat16 As[64][40];
    __shared__ __align__(16) __hip_bfloat16 Bs[64][40];   // Bs[n][k]
    const int tid = threadIdx.x;
    const int m0 = blockIdx.x * 64, n0 = blockIdx.y * 64;
    const int wave = tid >> 6, lane = tid & 63;
    const int wr = wave >> 1, wc = wave & 1;
    const int srow = tid >> 2, kseg = (tid & 3) * 8;

    int rA = 0, rB = 0, rG = 0;
    if constexpr (AMODE == EGEN) {
        int eg = eoff + m0 + srow;
        int a = ei[eg];
        rA = a * FDIM;
        rB = ei[EDGES + eg] * FDIM;
        rG = batch[a] * FDIM;
    }
    if constexpr (AMODE == ECLS) {
        rG = batch[ei[eoff + m0 + srow]] * FDIM;
    }
    float a0 = 0.f, a1 = 0.f;
    if constexpr (AMODE == ECLS) { a0 = attn[0]; a1 = attn[1]; }

    f32x4 acc[2][2] = {};
    for (int k0 = 0; k0 < K; k0 += 32) {
        int kg = k0 + kseg;
        // ---- stage A tile (64 rows x 32 k) ----
        uint4 av;
        if constexpr (AMODE == EGEN) {
            const __hip_bfloat16* src;
            int kk;
            if (kg < FDIM)            { src = xb + rA;  kk = kg; }
            else if (kg < 2 * FDIM)   { src = xb + rB;  kk = kg - FDIM; }
            else                      { src = geb + rG; kk = kg - 2 * FDIM; }
            av = *(const uint4*)(src + kk);
        } else if constexpr (AMODE == ECLS) {
            if (kg < FDIM) {
                uint4 u = *(const uint4*)(Asrc + (size_t)(m0 + srow) * FDIM + kg);
                uint4 s = *(const uint4*)(sij + (size_t)(eoff + m0 + srow) * FDIM + kg);
                av.x = bf2_combine(u.x, s.x, a0, a1);
                av.y = bf2_combine(u.y, s.y, a0, a1);
                av.z = bf2_combine(u.z, s.z, a0, a1);
                av.w = bf2_combine(u.w, s.w, a0, a1);
            } else {
                av = *(const uint4*)(geb + rG + kg - FDIM);
            }
        } else {
            av = *(const uint4*)(Asrc + (size_t)(m0 + srow) * K + kg);
        }
        *(uint4*)&As[srow][kseg] = av;
        // ---- stage B tile (64 cols x 32 k) ----
        uint4 bv = *(const uint4*)(Bt + (size_t)(n0 + srow) * K + kg);
        *(uint4*)&Bs[srow][kseg] = bv;
        __syncthreads();
        // ---- fragments + MFMA ----
        const int fr = lane & 15, krow = (lane >> 4) * 8;
        bf16x8 af0 = *(const bf16x8*)&As[wr * 32 + fr][krow];
        bf16x8 af1 = *(const bf16x8*)&As[wr * 32 + 16 + fr][krow];
        bf16x8 bf0 = *(const bf16x8*)&Bs[wc * 32 + fr][krow];
        bf16x8 bf1 = *(const bf16x8*)&Bs[wc * 32 + 16 + fr][krow];
        acc[0][0] = __builtin_amdgcn_mfma_f32_16x16x32_bf16(af0, bf0, acc[0][0], 0, 0, 0);
        acc[0][1] = __builtin_amdgcn_mfma_f32_16x16x32_bf16(af0, bf1, acc[0][1], 0, 0, 0);
        acc[1][0] = __builtin_amdgcn_mfma_f32_16x16x32_bf16(af1, bf0, acc[1][0], 0, 0, 0);
        acc[1][1] = __builtin_amdgcn_mfma_f32_16x16x32_bf16(af1, bf1, acc[1][1], 0, 0, 0);
        __syncthreads();
    }
    // ---- epilogue: bias + relu, bf16 store ----
    const int fr = lane & 15, rq = lane >> 4;
    #pragma unroll
    for (int i = 0; i < 2; ++i) {
        #pragma unroll
        for (int j = 0; j < 2; ++j) {
            int col = n0 + wc * 32 + j * 16 + fr;
            float bcol = bias[col];
            #pragma unroll
            for (int r = 0; r < 4; ++r) {
                int row = m0 + wr * 32 + i * 16 + rq * 4 + r;
                float v = acc[i][j][r] + bcol;
                v = fmaxf(v, 0.f);
                C[(size_t)row * NN + col] = __float2bfloat16(v);
            }
        }
    }
}

// ---------------- final classifier layer 2 (chunked, bf16 T) ----------------
__global__ void classifier2b(const __hip_bfloat16* __restrict__ T, const float* __restrict__ w2,
                             const float* __restrict__ b2, float* __restrict__ out, int eoff)
{
    int w = (blockIdx.x * 256 + threadIdx.x) >> 6;
    int lane = threadIdx.x & 63;
    if (w >= CH) return;
    unsigned tv = *(const unsigned*)(T + (size_t)w * 128 + lane * 2);
    float2 wv = *(const float2*)(w2 + lane * 2);
    float r = bflo(tv) * wv.x + bfhi(tv) * wv.y;
    #pragma unroll
    for (int o = 32; o > 0; o >>= 1) r += __shfl_down(r, o, 64);
    if (lane == 0) out[eoff + w] = sigmoidf_(r + b2[0]);
}

// =======================================================================================
extern "C" void kernel_launch(void* const* d_in, const int* in_sizes, int n_in,
                              void* d_out, int out_size, void* d_ws, size_t ws_size,
                              hipStream_t stream)
{
    const float* x     = (const float*)d_in[0];
    const float* ge    = (const float*)d_in[1];
    const int*   ei    = (const int*)d_in[2];
    const int*   batch = (const int*)d_in[4];
    const int*   he    = (const int*)d_in[5];
    const float* hw_w1 = (const float*)d_in[6];
    const float* hw_b1 = (const float*)d_in[7];
    const float* hw_w2 = (const float*)d_in[8];
    const float* hw_b2 = (const float*)d_in[9];
    const float* c1_w  = (const float*)d_in[10];
    const float* c1_b  = (const float*)d_in[11];
    const float* c2_w  = (const float*)d_in[12];
    const float* c2_b  = (const float*)d_in[13];
    const float* g_w1  = (const float*)d_in[14];
    const float* g_b1  = (const float*)d_in[15];
    const float* g_w2  = (const float*)d_in[16];
    const float* g_b2  = (const float*)d_in[17];
    const float* cl_w1 = (const float*)d_in[18];
    const float* cl_b1 = (const float*)d_in[19];
    const float* cl_w2 = (const float*)d_in[20];
    const float* cl_b2 = (const float*)d_in[21];
    const float* attn  = (const float*)d_in[22];
    float* out = (float*)d_out;

    char* ws = (char*)d_ws;
    size_t off = 0;
    auto alloc = [&](size_t nb) -> void* {
        off = (off + 255) & ~(size_t)255;
        void* p = ws + off;
        off += nb;
        return p;
    };
    // small arrays (~9.5 MB)
    float* node_w = (float*)alloc((size_t)NODES * 4);
    float* D      = (float*)alloc((size_t)EDGES * 4);   // becomes Dinv in place
    int*   Bcnt   = (int*)  alloc((size_t)NODES * 4);
    float* Binv   = (float*)alloc((size_t)NODES * 4);
    int*   rowCnt = (int*)  alloc((size_t)EDGES * 4);
    int*   colOff = (int*)  alloc((size_t)(NODES + 1) * 4);
    int*   rowOff = (int*)  alloc((size_t)(EDGES + 1) * 4);
    int*   colCur = (int*)  alloc((size_t)NODES * 4);
    int*   rowCur = (int*)  alloc((size_t)EDGES * 4);
    int*   colList= (int*)  alloc((size_t)NNZ_ * 4);
    int*   rowList= (int*)  alloc((size_t)NNZ_ * 4);
    int*   partA  = (int*)  alloc(1024 * 4);
    int*   partB  = (int*)  alloc(1024 * 4);
    // bf16 conversions (~5 MB)
    __hip_bfloat16* xb    = (__hip_bfloat16*)alloc((size_t)NODES * FDIM * 2);
    __hip_bfloat16* geb   = (__hip_bfloat16*)alloc((size_t)512 * FDIM * 2);
    __hip_bfloat16* gw1t  = (__hip_bfloat16*)alloc((size_t)512 * 384 * 2);
    __hip_bfloat16* gw2t  = (__hip_bfloat16*)alloc((size_t)128 * 512 * 2);
    __hip_bfloat16* clw1t = (__hip_bfloat16*)alloc((size_t)128 * 256 * 2);
    // big buffers (~172 MB)
    float* agg    = (float*)alloc((size_t)NODES * 256 * 4);   // agg1/agg2; later Tc bf16 [CH][128]
    void*  bufOX  = alloc((size_t)NODES * 256 * 4);           // oe1 bf16; later xl2c bf16 [CH][128]
    void*  oe2b   = alloc((size_t)NODES * 128 * 4);           // oe2 bf16 (half used)
    __hip_bfloat16* sij = (__hip_bfloat16*)alloc((size_t)EDGES * 128 * 2);
    __hip_bfloat16* xlc = (__hip_bfloat16*)alloc((size_t)CH * 512 * 2);

    __hip_bfloat16* oe1b = (__hip_bfloat16*)bufOX;   // [NODES][256] bf16
    __hip_bfloat16* xl2c = (__hip_bfloat16*)bufOX;   // [CH][128] bf16 (after oe1 consumed)
    __hip_bfloat16* Tc   = (__hip_bfloat16*)agg;     // [CH][128] bf16 (after agg consumed)
    __hip_bfloat16* oe2  = (__hip_bfloat16*)oe2b;    // [NODES][128] bf16
    // er [EDGES][256] bf16 = 131072000 B, exactly overlays sij (65.536 MB) + xlc (65.536 MB),
    // both dead until after col_agg_er.
    __hip_bfloat16* er   = sij;

    hipMemsetAsync(D, 0, (size_t)EDGES * 4, stream);
    hipMemsetAsync(Bcnt, 0, (size_t)NODES * 4, stream);
    hipMemsetAsync(rowCnt, 0, (size_t)EDGES * 4, stream);
    hipMemsetAsync(colCur, 0, (size_t)NODES * 4, stream);
    hipMemsetAsync(rowCur, 0, (size_t)EDGES * 4, stream);

    hyperweight_k<<<NODES / 8, 128, 0, stream>>>(x, ge, batch, hw_w1, hw_b1, hw_w2, hw_b2, node_w);
    incidence_pass<<<NNZ_ / 256, 256, 0, stream>>>(he, node_w, D, Bcnt, rowCnt);
    dinv_k<<<EDGES / 256, 256, 0, stream>>>(D);
    binv_k<<<(NODES + 255) / 256, 256, 0, stream>>>(Bcnt, Binv);

    const int ncN = (NODES + 1023) / 1024;
    const int ncE = (EDGES + 1023) / 1024;
    reduce_chunks<<<ncN, 1024, 0, stream>>>(Bcnt, partA, NODES);
    scan_sums<<<1, 1024, 0, stream>>>(partA, ncN);
    scan_chunks<<<ncN, 1024, 0, stream>>>(Bcnt, partA, colOff, NODES);
    reduce_chunks<<<ncE, 1024, 0, stream>>>(rowCnt, partB, EDGES);
    scan_sums<<<1, 1024, 0, stream>>>(partB, ncE);
    scan_chunks<<<ncE, 1024, 0, stream>>>(rowCnt, partB, rowOff, EDGES);
    scatter_pass<<<NNZ_ / 256, 256, 0, stream>>>(he, colOff, rowOff, colCur, rowCur, colList, rowList);

    // bf16 conversions / weight transposes
    conv_bf16<<<(NODES * FDIM + 255) / 256, 256, 0, stream>>>(x, xb, NODES * FDIM);
    conv_bf16<<<(512 * FDIM + 255) / 256, 256, 0, stream>>>(ge, geb, 512 * FDIM);
    transpose_bf16<<<(384 * 512 + 255) / 256, 256, 0, stream>>>(g_w1, gw1t, 384, 512);
    transpose_bf16<<<(512 * 128 + 255) / 256, 256, 0, stream>>>(g_w2, gw2t, 512, 128);
    transpose_bf16<<<(256 * 128 + 255) / 256, 256, 0, stream>>>(cl_w1, clw1t, 256, 128);

    // conv1 (linear-commuted): oe1 = Binv ⊙ (agg1 @ c1_w)   [NODES,256] bf16
    col_gather_x<<<NODES, 128, 0, stream>>>(xb, ei, colOff, colList, agg);
    gemm_node<256, 256, true><<<dim3(NODES / 64, 4), 256, 0, stream>>>(agg, c1_w, Binv, oe1b);

    // conv2: er materialized (parallel over edges), then flat col-aggregation
    er_k<<<EDGES, 128, 0, stream>>>(oe1b, rowOff, rowList, D, c1_b, er);
    col_agg_er<<<NODES, 128, 0, stream>>>(er, colOff, colList, agg);
    gemm_node<256, 128, true><<<dim3(NODES / 64, 2), 256, 0, stream>>>(agg, c2_w, Binv, oe2);

    // sij[e] = sigmoid(Dinv[e] * rowsum(oe2) + c2_b)   [EDGES,128] bf16  (overwrites er)
    sij_k<<<EDGES / 4, 256, 0, stream>>>(oe2, rowOff, rowList, D, c2_b, sij);

    // per-edge tail, chunked, all bf16 MFMA
    for (int c = 0; c < EDGES / CH; ++c) {
        int eoff = c * CH;
        gemm_edge_mfma<384, EGEN, 512><<<dim3(CH / 64, 8), 256, 0, stream>>>(
            nullptr, gw1t, g_b1, xlc, ei, batch, xb, geb, nullptr, nullptr, eoff);
        gemm_edge_mfma<512, EDIR, 128><<<dim3(CH / 64, 2), 256, 0, stream>>>(
            xlc, gw2t, g_b2, xl2c, nullptr, nullptr, nullptr, nullptr, nullptr, nullptr, eoff);
        gemm_edge_mfma<256, ECLS, 128><<<dim3(CH / 64, 2), 256, 0, stream>>>(
            xl2c, clw1t, cl_b1, Tc, ei, batch, nullptr, geb, sij, attn, eoff);
        classifier2b<<<CH / 4, 256, 0, stream>>>(Tc, cl_w2, cl_b2, out, eoff);
    }
}

// Round 8
// 810.530 us; speedup vs baseline: 4.4497x; 1.3328x over previous
//
#include <hip/hip_runtime.h>
#include <hip/hip_bf16.h>

#define NODES  16000
#define FDIM   128
#define EDGES  256000
#define NNZ_   512000

typedef __attribute__((ext_vector_type(8))) short bf16x8;
typedef __attribute__((ext_vector_type(4))) float f32x4;

__device__ __forceinline__ float sigmoidf_(float z) { return 1.f / (1.f + __expf(-z)); }
__device__ __forceinline__ float bflo(unsigned u) { return __uint_as_float(u << 16); }
__device__ __forceinline__ float bfhi(unsigned u) { return __uint_as_float(u & 0xffff0000u); }
__device__ __forceinline__ unsigned pack2(float lo, float hi) {
    __hip_bfloat162 h;
    h.x = __float2bfloat16(lo);
    h.y = __float2bfloat16(hi);
    return *(unsigned*)&h;
}

// ---------------- HyperWeight ----------------
__global__ __launch_bounds__(128) void hyperweight_k(
    const float* __restrict__ x, const float* __restrict__ ge, const int* __restrict__ batch,
    const float* __restrict__ w1, const float* __restrict__ b1,
    const float* __restrict__ w2, const float* __restrict__ b2, float* __restrict__ node_w)
{
    __shared__ float a[8][256];
    __shared__ float red[128];
    const int t = threadIdx.x;
    const int nb = blockIdx.x * 8;
    for (int u = 0; u < 8; ++u) {
        int n = nb + u;
        a[u][t]       = x[(size_t)n * FDIM + t];
        a[u][128 + t] = ge[(size_t)batch[n] * FDIM + t];
    }
    __syncthreads();
    float acc[8] = {0,0,0,0,0,0,0,0};
    for (int k = 0; k < 256; ++k) {
        float wv = w1[k * 128 + t];
        #pragma unroll
        for (int u = 0; u < 8; ++u) acc[u] += a[u][k] * wv;
    }
    const float wv2 = w2[t];
    for (int u = 0; u < 8; ++u) {
        float h = fmaxf(acc[u] + b1[t], 0.f);
        red[t] = h * wv2;
        __syncthreads();
        for (int s2 = 64; s2 > 0; s2 >>= 1) {
            if (t < s2) red[t] += red[t + s2];
            __syncthreads();
        }
        if (t == 0) node_w[nb + u] = sigmoidf_(red[0] + b2[0]);
        __syncthreads();
    }
}

// ---------------- incidence pass ----------------
__global__ void incidence_pass(const int* __restrict__ he, const float* __restrict__ node_w,
                               float* __restrict__ D, int* __restrict__ Bcnt, int* __restrict__ rowCnt)
{
    int i = blockIdx.x * 256 + threadIdx.x;
    if (i >= NNZ_) return;
    int hr = he[i];
    int hc = he[NNZ_ + i];
    int hc2 = he[NNZ_ + hc];              // repo quirk: w = node_w[hcol[hcol[i]]]
    atomicAdd(&D[hr], node_w[hc2]);
    atomicAdd(&Bcnt[hc], 1);
    atomicAdd(&rowCnt[hr], 1);
}

__global__ void dinv_k(float* __restrict__ D) {
    int e = blockIdx.x * 256 + threadIdx.x;
    if (e >= EDGES) return;
    float d = D[e];
    D[e] = (d != 0.f) ? 1.f / d : 0.f;
}
__global__ void binv_k(const int* __restrict__ Bcnt, float* __restrict__ Binv) {
    int n = blockIdx.x * 256 + threadIdx.x;
    if (n >= NODES) return;
    int c = Bcnt[n];
    Binv[n] = c ? 1.f / (float)c : 0.f;
}

// ---------------- exclusive scan (3-kernel) ----------------
__global__ __launch_bounds__(1024) void reduce_chunks(const int* __restrict__ in, int* __restrict__ part, int n) {
    __shared__ int s[1024];
    int t = threadIdx.x, g = blockIdx.x * 1024 + t;
    s[t] = (g < n) ? in[g] : 0;
    __syncthreads();
    for (int d = 512; d > 0; d >>= 1) {
        if (t < d) s[t] += s[t + d];
        __syncthreads();
    }
    if (t == 0) part[blockIdx.x] = s[0];
}
__global__ __launch_bounds__(1024) void scan_sums(int* __restrict__ part, int nc) {
    __shared__ int s[1024];
    int t = threadIdx.x;
    int v = (t < nc) ? part[t] : 0;
    s[t] = v;
    __syncthreads();
    for (int d = 1; d < 1024; d <<= 1) {
        int tv = (t >= d) ? s[t - d] : 0;
        __syncthreads();
        s[t] += tv;
        __syncthreads();
    }
    if (t < nc) part[t] = s[t] - v;     // exclusive
}
__global__ __launch_bounds__(1024) void scan_chunks(const int* __restrict__ in, const int* __restrict__ part,
                                                    int* __restrict__ out, int n) {
    __shared__ int s[1024];
    int t = threadIdx.x, g = blockIdx.x * 1024 + t;
    int v = (g < n) ? in[g] : 0;
    s[t] = v;
    __syncthreads();
    for (int d = 1; d < 1024; d <<= 1) {
        int tv = (t >= d) ? s[t - d] : 0;
        __syncthreads();
        s[t] += tv;
        __syncthreads();
    }
    int excl = s[t] - v + part[blockIdx.x];
    if (g < n) out[g] = excl;
    if (g == n - 1) out[n] = excl + v;
}

// ---------------- scatter into CSR lists ----------------
__global__ void scatter_pass(const int* __restrict__ he, const int* __restrict__ colOff, const int* __restrict__ rowOff,
                             int* __restrict__ colCur, int* __restrict__ rowCur,
                             int* __restrict__ colList, int* __restrict__ rowList)
{
    int i = blockIdx.x * 256 + threadIdx.x;
    if (i >= NNZ_) return;
    int hr = he[i];
    int hc = he[NNZ_ + i];
    int p = colOff[hc] + atomicAdd(&colCur[hc], 1);
    colList[p] = hr;
    int q = rowOff[hr] + atomicAdd(&rowCur[hr], 1);
    rowList[q] = hc;
}

// ---------------- fp32 -> bf16 conversion helpers ----------------
__global__ void conv_bf16(const float* __restrict__ in, __hip_bfloat16* __restrict__ out, int n) {
    int i = blockIdx.x * 256 + threadIdx.x;
    if (i < n) out[i] = __float2bfloat16(in[i]);
}
// in [K][N] fp32 -> out [N][K] bf16
__global__ void transpose_bf16(const float* __restrict__ in, __hip_bfloat16* __restrict__ out, int K, int N) {
    int i = blockIdx.x * 256 + threadIdx.x;
    if (i >= K * N) return;
    int n = i / K, k = i - n * K;
    out[i] = __float2bfloat16(in[k * N + n]);
}

// ---------------- agg1[n,256] = sum over edges r in col(n) of [xb[ei0[r]] | xb[ei1[r]]] ----
__global__ __launch_bounds__(128) void col_gather_x(
    const __hip_bfloat16* __restrict__ xb, const int* __restrict__ ei,
    const int* __restrict__ colOff, const int* __restrict__ colList, float* __restrict__ agg)
{
    int n = blockIdx.x;
    int t = threadIdx.x;
    int base = (t < 64) ? 0 : EDGES;
    int f = t & 63;
    const unsigned* x32 = (const unsigned*)xb;
    int s = colOff[n], e = colOff[n + 1];
    float vx = 0.f, vy = 0.f;
    int j = s;
    for (; j + 3 < e; j += 4) {
        int r0 = colList[j], r1 = colList[j + 1], r2 = colList[j + 2], r3 = colList[j + 3];
        unsigned q0 = x32[(size_t)ei[base + r0] * 64 + f];
        unsigned q1 = x32[(size_t)ei[base + r1] * 64 + f];
        unsigned q2 = x32[(size_t)ei[base + r2] * 64 + f];
        unsigned q3 = x32[(size_t)ei[base + r3] * 64 + f];
        vx += bflo(q0) + bflo(q1) + bflo(q2) + bflo(q3);
        vy += bfhi(q0) + bfhi(q1) + bfhi(q2) + bfhi(q3);
    }
    for (; j < e; ++j) {
        unsigned q0 = x32[(size_t)ei[base + colList[j]] * 64 + f];
        vx += bflo(q0); vy += bfhi(q0);
    }
    int ob = (t < 64) ? 0 : 128;
    float2 o = make_float2(vx, vy);
    *(float2*)(agg + (size_t)n * 256 + ob + 2 * f) = o;
}

// ---------------- er[r,256] (bf16) = sigmoid(Dinv[r]*rowsum(oe1) + c1_b) ----------------
__global__ __launch_bounds__(128) void er_k(
    const __hip_bfloat16* __restrict__ oe1, const int* __restrict__ rowOff,
    const int* __restrict__ rowList, const float* __restrict__ Dinv,
    const float* __restrict__ c1b, __hip_bfloat16* __restrict__ er)
{
    int r = blockIdx.x;
    int t = threadIdx.x;
    int s = rowOff[r], e = rowOff[r + 1];
    const unsigned* o32 = (const unsigned*)oe1;
    float vx = 0.f, vy = 0.f;
    int j = s;
    for (; j + 1 < e; j += 2) {
        unsigned q0 = o32[(size_t)rowList[j] * 128 + t];
        unsigned q1 = o32[(size_t)rowList[j + 1] * 128 + t];
        vx += bflo(q0) + bflo(q1);
        vy += bfhi(q0) + bfhi(q1);
    }
    if (j < e) {
        unsigned q0 = o32[(size_t)rowList[j] * 128 + t];
        vx += bflo(q0); vy += bfhi(q0);
    }
    float dv = Dinv[r];
    *(unsigned*)(er + (size_t)r * 256 + 2 * t) =
        pack2(sigmoidf_(dv * vx + c1b[2 * t]), sigmoidf_(dv * vy + c1b[2 * t + 1]));
}

// ---------------- agg2[n,256] = sum over r in col(n) of er[r] ----------------
__global__ __launch_bounds__(128) void col_agg_er(
    const __hip_bfloat16* __restrict__ er, const int* __restrict__ colOff,
    const int* __restrict__ colList, float* __restrict__ agg)
{
    int n = blockIdx.x;
    int t = threadIdx.x;
    const unsigned* e32 = (const unsigned*)er;
    int s = colOff[n], e = colOff[n + 1];
    float vx = 0.f, vy = 0.f;
    int j = s;
    for (; j + 3 < e; j += 4) {
        unsigned q0 = e32[(size_t)colList[j]     * 128 + t];
        unsigned q1 = e32[(size_t)colList[j + 1] * 128 + t];
        unsigned q2 = e32[(size_t)colList[j + 2] * 128 + t];
        unsigned q3 = e32[(size_t)colList[j + 3] * 128 + t];
        vx += bflo(q0) + bflo(q1) + bflo(q2) + bflo(q3);
        vy += bfhi(q0) + bfhi(q1) + bfhi(q2) + bfhi(q3);
    }
    for (; j < e; ++j) {
        unsigned q0 = e32[(size_t)colList[j] * 128 + t];
        vx += bflo(q0); vy += bfhi(q0);
    }
    float2 o = make_float2(vx, vy);
    *(float2*)(agg + (size_t)n * 256 + 2 * t) = o;
}

// ---------------- node-rows fp32 GEMM: C = rowscale ⊙ (A @ B) ----------------
template<int K, int NN, bool OB16>
__global__ __launch_bounds__(256) void gemm_node(
    const float* __restrict__ A, const float* __restrict__ B,
    const float* __restrict__ rowscale, void* __restrict__ C)
{
    __shared__ float As[16][68];
    __shared__ float Bs[16][68];
    const int tid = threadIdx.x;
    const int m0 = blockIdx.x * 64, n0 = blockIdx.y * 64;
    const int la_k = tid & 15, la_m = tid >> 4;
    const int lb_n = tid & 63, lb_k = tid >> 6;
    const int tn = tid & 15, tm = tid >> 4;
    float acc[4][4] = {};
    for (int k0 = 0; k0 < K; k0 += 16) {
        #pragma unroll
        for (int r = 0; r < 4; ++r)
            As[la_k][la_m + 16 * r] = A[(size_t)(m0 + la_m + 16 * r) * K + k0 + la_k];
        #pragma unroll
        for (int r = 0; r < 4; ++r)
            Bs[lb_k + 4 * r][lb_n] = B[(size_t)(k0 + lb_k + 4 * r) * NN + n0 + lb_n];
        __syncthreads();
        #pragma unroll
        for (int kk = 0; kk < 16; ++kk) {
            float4 av = *(const float4*)&As[kk][tm * 4];
            float4 bv = *(const float4*)&Bs[kk][tn * 4];
            float am[4] = {av.x, av.y, av.z, av.w};
            float bn[4] = {bv.x, bv.y, bv.z, bv.w};
            #pragma unroll
            for (int i = 0; i < 4; ++i)
                #pragma unroll
                for (int j = 0; j < 4; ++j)
                    acc[i][j] += am[i] * bn[j];
        }
        __syncthreads();
    }
    #pragma unroll
    for (int i = 0; i < 4; ++i) {
        int m = m0 + tm * 4 + i;
        float rs = rowscale[m];
        if constexpr (OB16) {
            __hip_bfloat16* Cp = (__hip_bfloat16*)C + (size_t)m * NN + n0 + tn * 4;
            #pragma unroll
            for (int j = 0; j < 4; ++j) Cp[j] = __float2bfloat16(rs * acc[i][j]);
        } else {
            float4 o = make_float4(rs * acc[i][0], rs * acc[i][1], rs * acc[i][2], rs * acc[i][3]);
            *(float4*)((float*)C + (size_t)m * NN + n0 + tn * 4) = o;
        }
    }
}

// ---------------- sij[e,128] (bf16) = sigmoid(Dinv[e]*rowsum(oe2) + c2_b) ----------------
__global__ void sij_k(const __hip_bfloat16* __restrict__ oe2, const int* __restrict__ rowOff,
                      const int* __restrict__ rowList, const float* __restrict__ Dinv,
                      const float* __restrict__ bias, __hip_bfloat16* __restrict__ sij)
{
    int w = (blockIdx.x * 256 + threadIdx.x) >> 6;
    int lane = threadIdx.x & 63;
    if (w >= EDGES) return;
    int s = rowOff[w], t = rowOff[w + 1];
    const unsigned* o32 = (const unsigned*)oe2;
    float ax = 0.f, ay = 0.f;
    for (int j = s; j < t; ++j) {
        unsigned q = o32[(size_t)rowList[j] * 64 + lane];
        ax += bflo(q); ay += bfhi(q);
    }
    float dv = Dinv[w];
    float2 b = *(const float2*)(bias + lane * 2);
    *(unsigned*)(sij + (size_t)w * 128 + lane * 2) =
        pack2(sigmoidf_(dv * ax + b.x), sigmoidf_(dv * ay + b.y));
}

// ---------------- generic bf16 MFMA GEMM, 64x128 tile, 2x2 waves: dst[M][512] ----------------
// A [M][K] bf16 contiguous; Bt rows are output-cols, row stride LDB; n0 = blockIdx.y*128.
template<int K, int LDB>
__global__ __launch_bounds__(256) void xw_mfma(
    const __hip_bfloat16* __restrict__ A, const __hip_bfloat16* __restrict__ Bt,
    __hip_bfloat16* __restrict__ dst)
{
    __shared__ __align__(16) __hip_bfloat16 As[64][40];
    __shared__ __align__(16) __hip_bfloat16 Bs[128][40];
    const int tid = threadIdx.x;
    const int m0 = blockIdx.x * 64, n0 = blockIdx.y * 128;
    const int wave = tid >> 6, lane = tid & 63;
    const int wr = wave >> 1, wc = wave & 1;
    const int srow = tid >> 2, kseg = (tid & 3) * 8;
    const int nr = tid >> 1, kb = (tid & 1) * 16;
    const int fr = lane & 15, krow = (lane >> 4) * 8, rq = lane >> 4;

    f32x4 acc[2][4] = {};
    for (int k0 = 0; k0 < K; k0 += 32) {
        *(uint4*)&As[srow][kseg] = *(const uint4*)(A + (size_t)(m0 + srow) * K + k0 + kseg);
        *(uint4*)&Bs[nr][kb]     = *(const uint4*)(Bt + (size_t)(n0 + nr) * LDB + k0 + kb);
        *(uint4*)&Bs[nr][kb + 8] = *(const uint4*)(Bt + (size_t)(n0 + nr) * LDB + k0 + kb + 8);
        __syncthreads();
        bf16x8 af[2], bf[4];
        #pragma unroll
        for (int i = 0; i < 2; ++i) af[i] = *(const bf16x8*)&As[wr * 32 + i * 16 + fr][krow];
        #pragma unroll
        for (int j = 0; j < 4; ++j) bf[j] = *(const bf16x8*)&Bs[wc * 64 + j * 16 + fr][krow];
        #pragma unroll
        for (int i = 0; i < 2; ++i)
            #pragma unroll
            for (int j = 0; j < 4; ++j)
                acc[i][j] = __builtin_amdgcn_mfma_f32_16x16x32_bf16(af[i], bf[j], acc[i][j], 0, 0, 0);
        __syncthreads();
    }
    #pragma unroll
    for (int i = 0; i < 2; ++i)
        #pragma unroll
        for (int j = 0; j < 4; ++j) {
            int col = n0 + wc * 64 + j * 16 + fr;
            #pragma unroll
            for (int r = 0; r < 4; ++r) {
                int row = m0 + wr * 32 + i * 16 + rq * 4 + r;
                dst[(size_t)row * 512 + col] = __float2bfloat16(acc[i][j][r]);
            }
        }
}

// ---------------- fused generator: xl2 = relu( relu(xa[col]+xb2[row]+gc[g]+b1) @ g_w2t + b2 )
__global__ __launch_bounds__(256) void gen2_mfma(
    const __hip_bfloat16* __restrict__ xa, const __hip_bfloat16* __restrict__ xb2,
    const __hip_bfloat16* __restrict__ gc, const float* __restrict__ b1,
    const __hip_bfloat16* __restrict__ gw2t, const float* __restrict__ b2,
    const int* __restrict__ ei, const int* __restrict__ batch,
    __hip_bfloat16* __restrict__ xl2)
{
    __shared__ __align__(16) __hip_bfloat16 As[64][40];
    __shared__ __align__(16) __hip_bfloat16 Bs[128][40];
    const int tid = threadIdx.x;
    const int m0 = blockIdx.x * 64;
    const int wave = tid >> 6, lane = tid & 63;
    const int wr = wave >> 1, wc = wave & 1;
    const int srow = tid >> 2, kseg = (tid & 3) * 8;
    const int nr = tid >> 1, kb = (tid & 1) * 16;
    const int fr = lane & 15, krow = (lane >> 4) * 8, rq = lane >> 4;

    const int eg = m0 + srow;
    const int c = ei[eg];
    const __hip_bfloat16* pa = xa  + (size_t)c * 512;
    const __hip_bfloat16* pb = xb2 + (size_t)ei[EDGES + eg] * 512;
    const __hip_bfloat16* pc = gc  + (size_t)batch[c] * 512;

    f32x4 acc[2][4] = {};
    for (int k0 = 0; k0 < 512; k0 += 32) {
        int kg = k0 + kseg;
        uint4 ua = *(const uint4*)(pa + kg);
        uint4 ub = *(const uint4*)(pb + kg);
        uint4 uc = *(const uint4*)(pc + kg);
        float4 f0 = *(const float4*)(b1 + kg);
        float4 f1 = *(const float4*)(b1 + kg + 4);
        uint4 av;
        av.x = pack2(fmaxf(bflo(ua.x) + bflo(ub.x) + bflo(uc.x) + f0.x, 0.f),
                     fmaxf(bfhi(ua.x) + bfhi(ub.x) + bfhi(uc.x) + f0.y, 0.f));
        av.y = pack2(fmaxf(bflo(ua.y) + bflo(ub.y) + bflo(uc.y) + f0.z, 0.f),
                     fmaxf(bfhi(ua.y) + bfhi(ub.y) + bfhi(uc.y) + f0.w, 0.f));
        av.z = pack2(fmaxf(bflo(ua.z) + bflo(ub.z) + bflo(uc.z) + f1.x, 0.f),
                     fmaxf(bfhi(ua.z) + bfhi(ub.z) + bfhi(uc.z) + f1.y, 0.f));
        av.w = pack2(fmaxf(bflo(ua.w) + bflo(ub.w) + bflo(uc.w) + f1.z, 0.f),
                     fmaxf(bfhi(ua.w) + bfhi(ub.w) + bfhi(uc.w) + f1.w, 0.f));
        *(uint4*)&As[srow][kseg] = av;
        *(uint4*)&Bs[nr][kb]     = *(const uint4*)(gw2t + (size_t)nr * 512 + k0 + kb);
        *(uint4*)&Bs[nr][kb + 8] = *(const uint4*)(gw2t + (size_t)nr * 512 + k0 + kb + 8);
        __syncthreads();
        bf16x8 af[2], bf[4];
        #pragma unroll
        for (int i = 0; i < 2; ++i) af[i] = *(const bf16x8*)&As[wr * 32 + i * 16 + fr][krow];
        #pragma unroll
        for (int j = 0; j < 4; ++j) bf[j] = *(const bf16x8*)&Bs[wc * 64 + j * 16 + fr][krow];
        #pragma unroll
        for (int i = 0; i < 2; ++i)
            #pragma unroll
            for (int j = 0; j < 4; ++j)
                acc[i][j] = __builtin_amdgcn_mfma_f32_16x16x32_bf16(af[i], bf[j], acc[i][j], 0, 0, 0);
        __syncthreads();
    }
    #pragma unroll
    for (int i = 0; i < 2; ++i)
        #pragma unroll
        for (int j = 0; j < 4; ++j) {
            int col = wc * 64 + j * 16 + fr;
            float bc = b2[col];
            #pragma unroll
            for (int r = 0; r < 4; ++r) {
                int row = m0 + wr * 32 + i * 16 + rq * 4 + r;
                xl2[(size_t)row * 128 + col] = __float2bfloat16(fmaxf(acc[i][j][r] + bc, 0.f));
            }
        }
}

// ---------------- fused classifier: out = sigmoid( relu([a0*xl2+a1*sij|gemb]@cl_w1t+b1)·w2 + b2 )
__global__ __launch_bounds__(256) void cls_mfma(
    const __hip_bfloat16* __restrict__ xl2, const __hip_bfloat16* __restrict__ sij,
    const __hip_bfloat16* __restrict__ geb, const float* __restrict__ attn,
    const __hip_bfloat16* __restrict__ clw1t, const float* __restrict__ b1,
    const float* __restrict__ w2, const float* __restrict__ b2,
    const int* __restrict__ ei, const int* __restrict__ batch,
    float* __restrict__ out)
{
    __shared__ __align__(16) __hip_bfloat16 As[64][40];
    __shared__ __align__(16) __hip_bfloat16 Bs[128][40];
    const int tid = threadIdx.x;
    const int m0 = blockIdx.x * 64;
    const int wave = tid >> 6, lane = tid & 63;
    const int srow = tid >> 2, kseg = (tid & 3) * 8;
    const int nr = tid >> 1, kb = (tid & 1) * 16;
    const int fr = lane & 15, krow = (lane >> 4) * 8, rq = lane >> 4;

    const int eg = m0 + srow;
    const int gi = batch[ei[eg]];
    const float a0 = attn[0], a1 = attn[1];

    f32x4 acc[8] = {};
    for (int k0 = 0; k0 < 256; k0 += 32) {
        int kg = k0 + kseg;
        uint4 av;
        if (kg < 128) {
            uint4 u = *(const uint4*)(xl2 + (size_t)eg * 128 + kg);
            uint4 s = *(const uint4*)(sij + (size_t)eg * 128 + kg);
            av.x = pack2(a0 * bflo(u.x) + a1 * bflo(s.x), a0 * bfhi(u.x) + a1 * bfhi(s.x));
            av.y = pack2(a0 * bflo(u.y) + a1 * bflo(s.y), a0 * bfhi(u.y) + a1 * bfhi(s.y));
            av.z = pack2(a0 * bflo(u.z) + a1 * bflo(s.z), a0 * bfhi(u.z) + a1 * bfhi(s.z));
            av.w = pack2(a0 * bflo(u.w) + a1 * bflo(s.w), a0 * bfhi(u.w) + a1 * bfhi(s.w));
        } else {
            av = *(const uint4*)(geb + (size_t)gi * 128 + kg - 128);
        }
        *(uint4*)&As[srow][kseg] = av;
        *(uint4*)&Bs[nr][kb]     = *(const uint4*)(clw1t + (size_t)nr * 256 + k0 + kb);
        *(uint4*)&Bs[nr][kb + 8] = *(const uint4*)(clw1t + (size_t)nr * 256 + k0 + kb + 8);
        __syncthreads();
        bf16x8 af = *(const bf16x8*)&As[wave * 16 + fr][krow];
        #pragma unroll
        for (int j = 0; j < 8; ++j) {
            bf16x8 bf = *(const bf16x8*)&Bs[j * 16 + fr][krow];
            acc[j] = __builtin_amdgcn_mfma_f32_16x16x32_bf16(af, bf, acc[j], 0, 0, 0);
        }
        __syncthreads();
    }
    // fused epilogue: relu(+b1) then dot with w2, 16-lane reduce, sigmoid
    float rsum[4] = {0.f, 0.f, 0.f, 0.f};
    #pragma unroll
    for (int j = 0; j < 8; ++j) {
        int colg = j * 16 + fr;
        float bc = b1[colg];
        float wv = w2[colg];
        #pragma unroll
        for (int r = 0; r < 4; ++r)
            rsum[r] += fmaxf(acc[j][r] + bc, 0.f) * wv;
    }
    #pragma unroll
    for (int m = 1; m < 16; m <<= 1) {
        #pragma unroll
        for (int r = 0; r < 4; ++r) rsum[r] += __shfl_xor(rsum[r], m, 64);
    }
    if (fr == 0) {
        float bb = b2[0];
        #pragma unroll
        for (int r = 0; r < 4; ++r)
            out[m0 + wave * 16 + rq * 4 + r] = sigmoidf_(rsum[r] + bb);
    }
}

// =======================================================================================
extern "C" void kernel_launch(void* const* d_in, const int* in_sizes, int n_in,
                              void* d_out, int out_size, void* d_ws, size_t ws_size,
                              hipStream_t stream)
{
    const float* x     = (const float*)d_in[0];
    const float* ge    = (const float*)d_in[1];
    const int*   ei    = (const int*)d_in[2];
    const int*   batch = (const int*)d_in[4];
    const int*   he    = (const int*)d_in[5];
    const float* hw_w1 = (const float*)d_in[6];
    const float* hw_b1 = (const float*)d_in[7];
    const float* hw_w2 = (const float*)d_in[8];
    const float* hw_b2 = (const float*)d_in[9];
    const float* c1_w  = (const float*)d_in[10];
    const float* c1_b  = (const float*)d_in[11];
    const float* c2_w  = (const float*)d_in[12];
    const float* c2_b  = (const float*)d_in[13];
    const float* g_w1  = (const float*)d_in[14];
    const float* g_b1  = (const float*)d_in[15];
    const float* g_w2  = (const float*)d_in[16];
    const float* g_b2  = (const float*)d_in[17];
    const float* cl_w1 = (const float*)d_in[18];
    const float* cl_b1 = (const float*)d_in[19];
    const float* cl_w2 = (const float*)d_in[20];
    const float* cl_b2 = (const float*)d_in[21];
    const float* attn  = (const float*)d_in[22];
    float* out = (float*)d_out;

    char* ws = (char*)d_ws;
    size_t off = 0;
    auto alloc = [&](size_t nb) -> void* {
        off = (off + 255) & ~(size_t)255;
        void* p = ws + off;
        off += nb;
        return p;
    };
    // small arrays (~9.5 MB)
    float* node_w = (float*)alloc((size_t)NODES * 4);
    float* D      = (float*)alloc((size_t)EDGES * 4);   // becomes Dinv in place
    int*   Bcnt   = (int*)  alloc((size_t)NODES * 4);
    float* Binv   = (float*)alloc((size_t)NODES * 4);
    int*   rowCnt = (int*)  alloc((size_t)EDGES * 4);
    int*   colOff = (int*)  alloc((size_t)(NODES + 1) * 4);
    int*   rowOff = (int*)  alloc((size_t)(EDGES + 1) * 4);
    int*   colCur = (int*)  alloc((size_t)NODES * 4);
    int*   rowCur = (int*)  alloc((size_t)EDGES * 4);
    int*   colList= (int*)  alloc((size_t)NNZ_ * 4);
    int*   rowList= (int*)  alloc((size_t)NNZ_ * 4);
    int*   partA  = (int*)  alloc(1024 * 4);
    int*   partB  = (int*)  alloc(1024 * 4);
    // bf16 conversions (~5 MB)
    __hip_bfloat16* xb    = (__hip_bfloat16*)alloc((size_t)NODES * FDIM * 2);
    __hip_bfloat16* geb   = (__hip_bfloat16*)alloc((size_t)512 * FDIM * 2);
    __hip_bfloat16* gw1t  = (__hip_bfloat16*)alloc((size_t)512 * 384 * 2);
    __hip_bfloat16* gw2t  = (__hip_bfloat16*)alloc((size_t)128 * 512 * 2);
    __hip_bfloat16* clw1t = (__hip_bfloat16*)alloc((size_t)128 * 256 * 2);
    // generator split tables (~33.5 MB)
    __hip_bfloat16* xa    = (__hip_bfloat16*)alloc((size_t)NODES * 512 * 2);
    __hip_bfloat16* xb2   = (__hip_bfloat16*)alloc((size_t)NODES * 512 * 2);
    __hip_bfloat16* gc    = (__hip_bfloat16*)alloc((size_t)512 * 512 * 2);
    // big buffers
    float* agg  = (float*)alloc((size_t)NODES * 256 * 4);            // 16.4 MB
    __hip_bfloat16* oe1b = (__hip_bfloat16*)alloc((size_t)NODES * 256 * 2);  // 8.2 MB
    __hip_bfloat16* oe2  = (__hip_bfloat16*)alloc((size_t)NODES * 128 * 2);  // 4.1 MB
    __hip_bfloat16* sij  = (__hip_bfloat16*)alloc((size_t)EDGES * 128 * 2);  // 65.5 MB
    __hip_bfloat16* xl2  = (__hip_bfloat16*)alloc((size_t)EDGES * 128 * 2);  // 65.5 MB (adjacent to sij)
    // er [EDGES][256] bf16 = 131 MB overlays sij+xl2 (both dead until after col_agg_er)
    __hip_bfloat16* er   = sij;

    hipMemsetAsync(D, 0, (size_t)EDGES * 4, stream);
    hipMemsetAsync(Bcnt, 0, (size_t)NODES * 4, stream);
    hipMemsetAsync(rowCnt, 0, (size_t)EDGES * 4, stream);
    hipMemsetAsync(colCur, 0, (size_t)NODES * 4, stream);
    hipMemsetAsync(rowCur, 0, (size_t)EDGES * 4, stream);

    hyperweight_k<<<NODES / 8, 128, 0, stream>>>(x, ge, batch, hw_w1, hw_b1, hw_w2, hw_b2, node_w);
    incidence_pass<<<NNZ_ / 256, 256, 0, stream>>>(he, node_w, D, Bcnt, rowCnt);
    dinv_k<<<EDGES / 256, 256, 0, stream>>>(D);
    binv_k<<<(NODES + 255) / 256, 256, 0, stream>>>(Bcnt, Binv);

    const int ncN = (NODES + 1023) / 1024;
    const int ncE = (EDGES + 1023) / 1024;
    reduce_chunks<<<ncN, 1024, 0, stream>>>(Bcnt, partA, NODES);
    scan_sums<<<1, 1024, 0, stream>>>(partA, ncN);
    scan_chunks<<<ncN, 1024, 0, stream>>>(Bcnt, partA, colOff, NODES);
    reduce_chunks<<<ncE, 1024, 0, stream>>>(rowCnt, partB, EDGES);
    scan_sums<<<1, 1024, 0, stream>>>(partB, ncE);
    scan_chunks<<<ncE, 1024, 0, stream>>>(rowCnt, partB, rowOff, EDGES);
    scatter_pass<<<NNZ_ / 256, 256, 0, stream>>>(he, colOff, rowOff, colCur, rowCur, colList, rowList);

    // bf16 conversions / weight transposes
    conv_bf16<<<(NODES * FDIM + 255) / 256, 256, 0, stream>>>(x, xb, NODES * FDIM);
    conv_bf16<<<(512 * FDIM + 255) / 256, 256, 0, stream>>>(ge, geb, 512 * FDIM);
    transpose_bf16<<<(384 * 512 + 255) / 256, 256, 0, stream>>>(g_w1, gw1t, 384, 512);
    transpose_bf16<<<(512 * 128 + 255) / 256, 256, 0, stream>>>(g_w2, gw2t, 512, 128);
    transpose_bf16<<<(256 * 128 + 255) / 256, 256, 0, stream>>>(cl_w1, clw1t, 256, 128);

    // generator split tables: xa = x@W[0:128], xb2 = x@W[128:256], gc = ge@W[256:384]
    xw_mfma<128, 384><<<dim3(NODES / 64, 4), 256, 0, stream>>>(xb, gw1t, xa);
    xw_mfma<128, 384><<<dim3(NODES / 64, 4), 256, 0, stream>>>(xb, gw1t + 128, xb2);
    xw_mfma<128, 384><<<dim3(512 / 64, 4), 256, 0, stream>>>(geb, gw1t + 256, gc);

    // conv1 (linear-commuted): oe1 = Binv ⊙ (agg1 @ c1_w)   [NODES,256] bf16
    col_gather_x<<<NODES, 128, 0, stream>>>(xb, ei, colOff, colList, agg);
    gemm_node<256, 256, true><<<dim3(NODES / 64, 4), 256, 0, stream>>>(agg, c1_w, Binv, oe1b);

    // conv2: er materialized, flat col-aggregation, oe2 = Binv ⊙ (agg2 @ c2_w)
    er_k<<<EDGES, 128, 0, stream>>>(oe1b, rowOff, rowList, D, c1_b, er);
    col_agg_er<<<NODES, 128, 0, stream>>>(er, colOff, colList, agg);
    gemm_node<256, 128, true><<<dim3(NODES / 64, 2), 256, 0, stream>>>(agg, c2_w, Binv, oe2);

    // sij[e] = sigmoid(Dinv[e]*rowsum(oe2) + c2_b)  (writes over first half of er region)
    sij_k<<<EDGES / 4, 256, 0, stream>>>(oe2, rowOff, rowList, D, c2_b, sij);

    // fused generator L2 (A computed from xa/xb2/gc gathers)  -> xl2
    gen2_mfma<<<EDGES / 64, 256, 0, stream>>>(xa, xb2, gc, g_b1, gw2t, g_b2, ei, batch, xl2);

    // fused classifier (GEMM + final dot + sigmoid) -> out
    cls_mfma<<<EDGES / 64, 256, 0, stream>>>(xl2, sij, geb, attn, clw1t, cl_b1, cl_w2, cl_b2,
                                             ei, batch, out);
}

// Round 9
// 770.512 us; speedup vs baseline: 4.6808x; 1.0519x over previous
//
#include <hip/hip_runtime.h>
#include <hip/hip_bf16.h>

#define NODES  16000
#define FDIM   128
#define EDGES  256000
#define NNZ_   512000

typedef __attribute__((ext_vector_type(8))) short bf16x8;
typedef __attribute__((ext_vector_type(4))) float f32x4;

__device__ __forceinline__ float sigmoidf_(float z) { return 1.f / (1.f + __expf(-z)); }
__device__ __forceinline__ float bflo(unsigned u) { return __uint_as_float(u << 16); }
__device__ __forceinline__ float bfhi(unsigned u) { return __uint_as_float(u & 0xffff0000u); }
__device__ __forceinline__ unsigned pack2(float lo, float hi) {
    __hip_bfloat162 h;
    h.x = __float2bfloat16(lo);
    h.y = __float2bfloat16(hi);
    return *(unsigned*)&h;
}

// ---------------- HyperWeight ----------------
__global__ __launch_bounds__(128) void hyperweight_k(
    const float* __restrict__ x, const float* __restrict__ ge, const int* __restrict__ batch,
    const float* __restrict__ w1, const float* __restrict__ b1,
    const float* __restrict__ w2, const float* __restrict__ b2, float* __restrict__ node_w)
{
    __shared__ float a[8][256];
    __shared__ float red[128];
    const int t = threadIdx.x;
    const int nb = blockIdx.x * 8;
    for (int u = 0; u < 8; ++u) {
        int n = nb + u;
        a[u][t]       = x[(size_t)n * FDIM + t];
        a[u][128 + t] = ge[(size_t)batch[n] * FDIM + t];
    }
    __syncthreads();
    float acc[8] = {0,0,0,0,0,0,0,0};
    for (int k = 0; k < 256; ++k) {
        float wv = w1[k * 128 + t];
        #pragma unroll
        for (int u = 0; u < 8; ++u) acc[u] += a[u][k] * wv;
    }
    const float wv2 = w2[t];
    for (int u = 0; u < 8; ++u) {
        float h = fmaxf(acc[u] + b1[t], 0.f);
        red[t] = h * wv2;
        __syncthreads();
        for (int s2 = 64; s2 > 0; s2 >>= 1) {
            if (t < s2) red[t] += red[t + s2];
            __syncthreads();
        }
        if (t == 0) node_w[nb + u] = sigmoidf_(red[0] + b2[0]);
        __syncthreads();
    }
}

// ---------------- incidence pass ----------------
__global__ void incidence_pass(const int* __restrict__ he, const float* __restrict__ node_w,
                               float* __restrict__ D, int* __restrict__ Bcnt, int* __restrict__ rowCnt)
{
    int i = blockIdx.x * 256 + threadIdx.x;
    if (i >= NNZ_) return;
    int hr = he[i];
    int hc = he[NNZ_ + i];
    int hc2 = he[NNZ_ + hc];              // repo quirk: w = node_w[hcol[hcol[i]]]
    atomicAdd(&D[hr], node_w[hc2]);
    atomicAdd(&Bcnt[hc], 1);
    atomicAdd(&rowCnt[hr], 1);
}

// fused: Dinv (edges) + Binv (nodes)
__global__ void inv_k(float* __restrict__ D, const int* __restrict__ Bcnt, float* __restrict__ Binv) {
    int i = blockIdx.x * 256 + threadIdx.x;
    if (i < EDGES) {
        float d = D[i];
        D[i] = (d != 0.f) ? 1.f / d : 0.f;
    }
    if (i < NODES) {
        int c = Bcnt[i];
        Binv[i] = c ? 1.f / (float)c : 0.f;
    }
}

// ---------------- exclusive scan (3-kernel) ----------------
__global__ __launch_bounds__(1024) void reduce_chunks(const int* __restrict__ in, int* __restrict__ part, int n) {
    __shared__ int s[1024];
    int t = threadIdx.x, g = blockIdx.x * 1024 + t;
    s[t] = (g < n) ? in[g] : 0;
    __syncthreads();
    for (int d = 512; d > 0; d >>= 1) {
        if (t < d) s[t] += s[t + d];
        __syncthreads();
    }
    if (t == 0) part[blockIdx.x] = s[0];
}
__global__ __launch_bounds__(1024) void scan_sums(int* __restrict__ part, int nc) {
    __shared__ int s[1024];
    int t = threadIdx.x;
    int v = (t < nc) ? part[t] : 0;
    s[t] = v;
    __syncthreads();
    for (int d = 1; d < 1024; d <<= 1) {
        int tv = (t >= d) ? s[t - d] : 0;
        __syncthreads();
        s[t] += tv;
        __syncthreads();
    }
    if (t < nc) part[t] = s[t] - v;     // exclusive
}
__global__ __launch_bounds__(1024) void scan_chunks(const int* __restrict__ in, const int* __restrict__ part,
                                                    int* __restrict__ out, int n) {
    __shared__ int s[1024];
    int t = threadIdx.x, g = blockIdx.x * 1024 + t;
    int v = (g < n) ? in[g] : 0;
    s[t] = v;
    __syncthreads();
    for (int d = 1; d < 1024; d <<= 1) {
        int tv = (t >= d) ? s[t - d] : 0;
        __syncthreads();
        s[t] += tv;
        __syncthreads();
    }
    int excl = s[t] - v + part[blockIdx.x];
    if (g < n) out[g] = excl;
    if (g == n - 1) out[n] = excl + v;
}

// ---------------- scatter into CSR lists ----------------
__global__ void scatter_pass(const int* __restrict__ he, const int* __restrict__ colOff, const int* __restrict__ rowOff,
                             int* __restrict__ colCur, int* __restrict__ rowCur,
                             int* __restrict__ colList, int* __restrict__ rowList)
{
    int i = blockIdx.x * 256 + threadIdx.x;
    if (i >= NNZ_) return;
    int hr = he[i];
    int hc = he[NNZ_ + i];
    int p = colOff[hc] + atomicAdd(&colCur[hc], 1);
    colList[p] = hr;
    int q = rowOff[hr] + atomicAdd(&rowCur[hr], 1);
    rowList[q] = hc;
}

// ---------------- fp32 -> bf16 conversion helpers ----------------
__global__ void conv_bf16(const float* __restrict__ in, __hip_bfloat16* __restrict__ out, int n) {
    int i = blockIdx.x * 256 + threadIdx.x;
    if (i < n) out[i] = __float2bfloat16(in[i]);
}
// in [K][N] fp32 -> out [N][K] bf16
__global__ void transpose_bf16(const float* __restrict__ in, __hip_bfloat16* __restrict__ out, int K, int N) {
    int i = blockIdx.x * 256 + threadIdx.x;
    if (i >= K * N) return;
    int n = i / K, k = i - n * K;
    out[i] = __float2bfloat16(in[k * N + n]);
}

// ---------------- agg1[n,256] = sum over edges r in col(n) of [xb[ei0[r]] | xb[ei1[r]]] ----
__global__ __launch_bounds__(128) void col_gather_x(
    const __hip_bfloat16* __restrict__ xb, const int* __restrict__ ei,
    const int* __restrict__ colOff, const int* __restrict__ colList, float* __restrict__ agg)
{
    int n = blockIdx.x;
    int t = threadIdx.x;
    int base = (t < 64) ? 0 : EDGES;
    int f = t & 63;
    const unsigned* x32 = (const unsigned*)xb;
    int s = colOff[n], e = colOff[n + 1];
    float vx = 0.f, vy = 0.f;
    int j = s;
    for (; j + 3 < e; j += 4) {
        int r0 = colList[j], r1 = colList[j + 1], r2 = colList[j + 2], r3 = colList[j + 3];
        unsigned q0 = x32[(size_t)ei[base + r0] * 64 + f];
        unsigned q1 = x32[(size_t)ei[base + r1] * 64 + f];
        unsigned q2 = x32[(size_t)ei[base + r2] * 64 + f];
        unsigned q3 = x32[(size_t)ei[base + r3] * 64 + f];
        vx += bflo(q0) + bflo(q1) + bflo(q2) + bflo(q3);
        vy += bfhi(q0) + bfhi(q1) + bfhi(q2) + bfhi(q3);
    }
    for (; j < e; ++j) {
        unsigned q0 = x32[(size_t)ei[base + colList[j]] * 64 + f];
        vx += bflo(q0); vy += bfhi(q0);
    }
    int ob = (t < 64) ? 0 : 128;
    float2 o = make_float2(vx, vy);
    *(float2*)(agg + (size_t)n * 256 + ob + 2 * f) = o;
}

// ---------------- er[r,256] (bf16) = sigmoid(Dinv[r]*rowsum(oe1) + c1_b) ----------------
__global__ __launch_bounds__(128) void er_k(
    const __hip_bfloat16* __restrict__ oe1, const int* __restrict__ rowOff,
    const int* __restrict__ rowList, const float* __restrict__ Dinv,
    const float* __restrict__ c1b, __hip_bfloat16* __restrict__ er)
{
    int r = blockIdx.x;
    int t = threadIdx.x;
    int s = rowOff[r], e = rowOff[r + 1];
    const unsigned* o32 = (const unsigned*)oe1;
    float vx = 0.f, vy = 0.f;
    int j = s;
    for (; j + 1 < e; j += 2) {
        unsigned q0 = o32[(size_t)rowList[j] * 128 + t];
        unsigned q1 = o32[(size_t)rowList[j + 1] * 128 + t];
        vx += bflo(q0) + bflo(q1);
        vy += bfhi(q0) + bfhi(q1);
    }
    if (j < e) {
        unsigned q0 = o32[(size_t)rowList[j] * 128 + t];
        vx += bflo(q0); vy += bfhi(q0);
    }
    float dv = Dinv[r];
    *(unsigned*)(er + (size_t)r * 256 + 2 * t) =
        pack2(sigmoidf_(dv * vx + c1b[2 * t]), sigmoidf_(dv * vy + c1b[2 * t + 1]));
}

// ---------------- agg2[n,256] = sum over r in col(n) of er[r] ----------------
__global__ __launch_bounds__(128) void col_agg_er(
    const __hip_bfloat16* __restrict__ er, const int* __restrict__ colOff,
    const int* __restrict__ colList, float* __restrict__ agg)
{
    int n = blockIdx.x;
    int t = threadIdx.x;
    const unsigned* e32 = (const unsigned*)er;
    int s = colOff[n], e = colOff[n + 1];
    float vx = 0.f, vy = 0.f;
    int j = s;
    for (; j + 3 < e; j += 4) {
        unsigned q0 = e32[(size_t)colList[j]     * 128 + t];
        unsigned q1 = e32[(size_t)colList[j + 1] * 128 + t];
        unsigned q2 = e32[(size_t)colList[j + 2] * 128 + t];
        unsigned q3 = e32[(size_t)colList[j + 3] * 128 + t];
        vx += bflo(q0) + bflo(q1) + bflo(q2) + bflo(q3);
        vy += bfhi(q0) + bfhi(q1) + bfhi(q2) + bfhi(q3);
    }
    for (; j < e; ++j) {
        unsigned q0 = e32[(size_t)colList[j] * 128 + t];
        vx += bflo(q0); vy += bfhi(q0);
    }
    float2 o = make_float2(vx, vy);
    *(float2*)(agg + (size_t)n * 256 + 2 * t) = o;
}

// ---------------- node-rows fp32 GEMM: C = rowscale ⊙ (A @ B) ----------------
template<int K, int NN, bool OB16>
__global__ __launch_bounds__(256) void gemm_node(
    const float* __restrict__ A, const float* __restrict__ B,
    const float* __restrict__ rowscale, void* __restrict__ C)
{
    __shared__ float As[16][68];
    __shared__ float Bs[16][68];
    const int tid = threadIdx.x;
    const int m0 = blockIdx.x * 64, n0 = blockIdx.y * 64;
    const int la_k = tid & 15, la_m = tid >> 4;
    const int lb_n = tid & 63, lb_k = tid >> 6;
    const int tn = tid & 15, tm = tid >> 4;
    float acc[4][4] = {};
    for (int k0 = 0; k0 < K; k0 += 16) {
        #pragma unroll
        for (int r = 0; r < 4; ++r)
            As[la_k][la_m + 16 * r] = A[(size_t)(m0 + la_m + 16 * r) * K + k0 + la_k];
        #pragma unroll
        for (int r = 0; r < 4; ++r)
            Bs[lb_k + 4 * r][lb_n] = B[(size_t)(k0 + lb_k + 4 * r) * NN + n0 + lb_n];
        __syncthreads();
        #pragma unroll
        for (int kk = 0; kk < 16; ++kk) {
            float4 av = *(const float4*)&As[kk][tm * 4];
            float4 bv = *(const float4*)&Bs[kk][tn * 4];
            float am[4] = {av.x, av.y, av.z, av.w};
            float bn[4] = {bv.x, bv.y, bv.z, bv.w};
            #pragma unroll
            for (int i = 0; i < 4; ++i)
                #pragma unroll
                for (int j = 0; j < 4; ++j)
                    acc[i][j] += am[i] * bn[j];
        }
        __syncthreads();
    }
    #pragma unroll
    for (int i = 0; i < 4; ++i) {
        int m = m0 + tm * 4 + i;
        float rs = rowscale[m];
        if constexpr (OB16) {
            __hip_bfloat16* Cp = (__hip_bfloat16*)C + (size_t)m * NN + n0 + tn * 4;
            #pragma unroll
            for (int j = 0; j < 4; ++j) Cp[j] = __float2bfloat16(rs * acc[i][j]);
        } else {
            float4 o = make_float4(rs * acc[i][0], rs * acc[i][1], rs * acc[i][2], rs * acc[i][3]);
            *(float4*)((float*)C + (size_t)m * NN + n0 + tn * 4) = o;
        }
    }
}

// ---------------- generic bf16 MFMA GEMM, 64x128 tile, 2x2 waves: dst[M][512] ----------------
template<int K, int LDB>
__global__ __launch_bounds__(256) void xw_mfma(
    const __hip_bfloat16* __restrict__ A, const __hip_bfloat16* __restrict__ Bt,
    __hip_bfloat16* __restrict__ dst)
{
    __shared__ __align__(16) __hip_bfloat16 As[64][40];
    __shared__ __align__(16) __hip_bfloat16 Bs[128][40];
    const int tid = threadIdx.x;
    const int m0 = blockIdx.x * 64, n0 = blockIdx.y * 128;
    const int wave = tid >> 6, lane = tid & 63;
    const int wr = wave >> 1, wc = wave & 1;
    const int srow = tid >> 2, kseg = (tid & 3) * 8;
    const int nr = tid >> 1, kb = (tid & 1) * 16;
    const int fr = lane & 15, krow = (lane >> 4) * 8, rq = lane >> 4;

    f32x4 acc[2][4] = {};
    for (int k0 = 0; k0 < K; k0 += 32) {
        *(uint4*)&As[srow][kseg] = *(const uint4*)(A + (size_t)(m0 + srow) * K + k0 + kseg);
        *(uint4*)&Bs[nr][kb]     = *(const uint4*)(Bt + (size_t)(n0 + nr) * LDB + k0 + kb);
        *(uint4*)&Bs[nr][kb + 8] = *(const uint4*)(Bt + (size_t)(n0 + nr) * LDB + k0 + kb + 8);
        __syncthreads();
        bf16x8 af[2], bf[4];
        #pragma unroll
        for (int i = 0; i < 2; ++i) af[i] = *(const bf16x8*)&As[wr * 32 + i * 16 + fr][krow];
        #pragma unroll
        for (int j = 0; j < 4; ++j) bf[j] = *(const bf16x8*)&Bs[wc * 64 + j * 16 + fr][krow];
        #pragma unroll
        for (int i = 0; i < 2; ++i)
            #pragma unroll
            for (int j = 0; j < 4; ++j)
                acc[i][j] = __builtin_amdgcn_mfma_f32_16x16x32_bf16(af[i], bf[j], acc[i][j], 0, 0, 0);
        __syncthreads();
    }
    #pragma unroll
    for (int i = 0; i < 2; ++i)
        #pragma unroll
        for (int j = 0; j < 4; ++j) {
            int col = n0 + wc * 64 + j * 16 + fr;
            #pragma unroll
            for (int r = 0; r < 4; ++r) {
                int row = m0 + wr * 32 + i * 16 + rq * 4 + r;
                dst[(size_t)row * 512 + col] = __float2bfloat16(acc[i][j][r]);
            }
        }
}

// ---------------- fused generator (pipelined): xl2 = relu(relu(xa+xb2+gc+b1) @ g_w2t + b2) ----
__global__ __launch_bounds__(256) void gen2_mfma(
    const __hip_bfloat16* __restrict__ xa, const __hip_bfloat16* __restrict__ xb2,
    const __hip_bfloat16* __restrict__ gc, const float* __restrict__ b1,
    const __hip_bfloat16* __restrict__ gw2t, const float* __restrict__ b2,
    const int* __restrict__ ei, const int* __restrict__ batch,
    __hip_bfloat16* __restrict__ xl2)
{
    __shared__ __align__(16) __hip_bfloat16 As[2][64][40];
    __shared__ __align__(16) __hip_bfloat16 Bs[2][128][40];
    const int tid = threadIdx.x;
    const int m0 = blockIdx.x * 64;
    const int wave = tid >> 6, lane = tid & 63;
    const int wr = wave >> 1, wc = wave & 1;
    const int srow = tid >> 2, kseg = (tid & 3) * 8;
    const int nr = tid >> 1, kb = (tid & 1) * 16;
    const int fr = lane & 15, krow = (lane >> 4) * 8, rq = lane >> 4;

    const int eg = m0 + srow;
    const int c = ei[eg];
    const __hip_bfloat16* pa = xa  + (size_t)c * 512;
    const __hip_bfloat16* pb = xb2 + (size_t)ei[EDGES + eg] * 512;
    const __hip_bfloat16* pc = gc  + (size_t)batch[c] * 512;

    uint4 ua, ub, uc, bv0, bv1;
    auto GLOAD = [&](int k0) {
        int kg = k0 + kseg;
        ua = *(const uint4*)(pa + kg);
        ub = *(const uint4*)(pb + kg);
        uc = *(const uint4*)(pc + kg);
        bv0 = *(const uint4*)(gw2t + (size_t)nr * 512 + k0 + kb);
        bv1 = *(const uint4*)(gw2t + (size_t)nr * 512 + k0 + kb + 8);
    };
    auto STORE = [&](int buf, int k0) {
        int kg = k0 + kseg;
        float4 f0 = *(const float4*)(b1 + kg);
        float4 f1 = *(const float4*)(b1 + kg + 4);
        uint4 av;
        av.x = pack2(fmaxf(bflo(ua.x) + bflo(ub.x) + bflo(uc.x) + f0.x, 0.f),
                     fmaxf(bfhi(ua.x) + bfhi(ub.x) + bfhi(uc.x) + f0.y, 0.f));
        av.y = pack2(fmaxf(bflo(ua.y) + bflo(ub.y) + bflo(uc.y) + f0.z, 0.f),
                     fmaxf(bfhi(ua.y) + bfhi(ub.y) + bfhi(uc.y) + f0.w, 0.f));
        av.z = pack2(fmaxf(bflo(ua.z) + bflo(ub.z) + bflo(uc.z) + f1.x, 0.f),
                     fmaxf(bfhi(ua.z) + bfhi(ub.z) + bfhi(uc.z) + f1.y, 0.f));
        av.w = pack2(fmaxf(bflo(ua.w) + bflo(ub.w) + bflo(uc.w) + f1.z, 0.f),
                     fmaxf(bfhi(ua.w) + bfhi(ub.w) + bfhi(uc.w) + f1.w, 0.f));
        *(uint4*)&As[buf][srow][kseg] = av;
        *(uint4*)&Bs[buf][nr][kb]     = bv0;
        *(uint4*)&Bs[buf][nr][kb + 8] = bv1;
    };

    GLOAD(0);
    STORE(0, 0);
    __syncthreads();

    f32x4 acc[2][4] = {};
    for (int it = 0; it < 16; ++it) {
        int cur = it & 1;
        if (it < 15) GLOAD((it + 1) * 32);
        bf16x8 af[2], bf[4];
        #pragma unroll
        for (int i = 0; i < 2; ++i) af[i] = *(const bf16x8*)&As[cur][wr * 32 + i * 16 + fr][krow];
        #pragma unroll
        for (int j = 0; j < 4; ++j) bf[j] = *(const bf16x8*)&Bs[cur][wc * 64 + j * 16 + fr][krow];
        #pragma unroll
        for (int i = 0; i < 2; ++i)
            #pragma unroll
            for (int j = 0; j < 4; ++j)
                acc[i][j] = __builtin_amdgcn_mfma_f32_16x16x32_bf16(af[i], bf[j], acc[i][j], 0, 0, 0);
        if (it < 15) STORE(cur ^ 1, (it + 1) * 32);
        __syncthreads();
    }
    #pragma unroll
    for (int i = 0; i < 2; ++i)
        #pragma unroll
        for (int j = 0; j < 4; ++j) {
            int col = wc * 64 + j * 16 + fr;
            float bc = b2[col];
            #pragma unroll
            for (int r = 0; r < 4; ++r) {
                int row = m0 + wr * 32 + i * 16 + rq * 4 + r;
                xl2[(size_t)row * 128 + col] = __float2bfloat16(fmaxf(acc[i][j][r] + bc, 0.f));
            }
        }
}

// ---------------- fused classifier (pipelined, sij computed inline from oe2) ----------------
// out = sigmoid( relu([a0*xl2 + a1*sigmoid(Dinv*rowsum(oe2)+c2b) | gemb] @ cl_w1t + b1)·w2 + b2 )
__global__ __launch_bounds__(256) void cls_mfma(
    const __hip_bfloat16* __restrict__ xl2, const __hip_bfloat16* __restrict__ oe2,
    const __hip_bfloat16* __restrict__ geb, const float* __restrict__ attn,
    const __hip_bfloat16* __restrict__ clw1t, const float* __restrict__ b1,
    const float* __restrict__ w2, const float* __restrict__ b2, const float* __restrict__ c2b,
    const int* __restrict__ ei, const int* __restrict__ batch,
    const int* __restrict__ rowOff, const int* __restrict__ rowList, const float* __restrict__ Dinv,
    float* __restrict__ out)
{
    __shared__ __align__(16) __hip_bfloat16 As[2][64][40];
    __shared__ __align__(16) __hip_bfloat16 Bs[2][128][40];
    const int tid = threadIdx.x;
    const int m0 = blockIdx.x * 64;
    const int wave = tid >> 6, lane = tid & 63;
    const int srow = tid >> 2, kseg = (tid & 3) * 8;
    const int nr = tid >> 1, kb = (tid & 1) * 16;
    const int fr = lane & 15, krow = (lane >> 4) * 8, rq = lane >> 4;

    const int eg = m0 + srow;
    const int gi = batch[ei[eg]];
    const float a0 = attn[0], a1 = attn[1];
    const int rs = rowOff[eg], re = rowOff[eg + 1];
    const float dv = Dinv[eg];

    uint4 avr, bv0, bv1;
    auto PREP = [&](int k0) {
        int kg = k0 + kseg;
        bv0 = *(const uint4*)(clw1t + (size_t)nr * 256 + k0 + kb);
        bv1 = *(const uint4*)(clw1t + (size_t)nr * 256 + k0 + kb + 8);
        if (kg < 128) {
            uint4 u = *(const uint4*)(xl2 + (size_t)eg * 128 + kg);
            float s0 = 0.f, s1 = 0.f, s2 = 0.f, s3 = 0.f, s4 = 0.f, s5 = 0.f, s6 = 0.f, s7 = 0.f;
            for (int q = rs; q < re; ++q) {
                uint4 o = *(const uint4*)(oe2 + (size_t)rowList[q] * 128 + kg);
                s0 += bflo(o.x); s1 += bfhi(o.x); s2 += bflo(o.y); s3 += bfhi(o.y);
                s4 += bflo(o.z); s5 += bfhi(o.z); s6 += bflo(o.w); s7 += bfhi(o.w);
            }
            float4 c0 = *(const float4*)(c2b + kg);
            float4 c1 = *(const float4*)(c2b + kg + 4);
            avr.x = pack2(a0 * bflo(u.x) + a1 * sigmoidf_(dv * s0 + c0.x),
                          a0 * bfhi(u.x) + a1 * sigmoidf_(dv * s1 + c0.y));
            avr.y = pack2(a0 * bflo(u.y) + a1 * sigmoidf_(dv * s2 + c0.z),
                          a0 * bfhi(u.y) + a1 * sigmoidf_(dv * s3 + c0.w));
            avr.z = pack2(a0 * bflo(u.z) + a1 * sigmoidf_(dv * s4 + c1.x),
                          a0 * bfhi(u.z) + a1 * sigmoidf_(dv * s5 + c1.y));
            avr.w = pack2(a0 * bflo(u.w) + a1 * sigmoidf_(dv * s6 + c1.z),
                          a0 * bfhi(u.w) + a1 * sigmoidf_(dv * s7 + c1.w));
        } else {
            avr = *(const uint4*)(geb + (size_t)gi * 128 + kg - 128);
        }
    };
    auto STORE = [&](int buf) {
        *(uint4*)&As[buf][srow][kseg] = avr;
        *(uint4*)&Bs[buf][nr][kb]     = bv0;
        *(uint4*)&Bs[buf][nr][kb + 8] = bv1;
    };

    PREP(0);
    STORE(0);
    __syncthreads();

    f32x4 acc[8] = {};
    for (int it = 0; it < 8; ++it) {
        int cur = it & 1;
        if (it < 7) PREP((it + 1) * 32);
        bf16x8 af = *(const bf16x8*)&As[cur][wave * 16 + fr][krow];
        #pragma unroll
        for (int j = 0; j < 8; ++j) {
            bf16x8 bf = *(const bf16x8*)&Bs[cur][j * 16 + fr][krow];
            acc[j] = __builtin_amdgcn_mfma_f32_16x16x32_bf16(af, bf, acc[j], 0, 0, 0);
        }
        if (it < 7) STORE(cur ^ 1);
        __syncthreads();
    }
    // fused epilogue: relu(+b1) then dot with w2, 16-lane reduce, sigmoid
    float rsum[4] = {0.f, 0.f, 0.f, 0.f};
    #pragma unroll
    for (int j = 0; j < 8; ++j) {
        int colg = j * 16 + fr;
        float bc = b1[colg];
        float wv = w2[colg];
        #pragma unroll
        for (int r = 0; r < 4; ++r)
            rsum[r] += fmaxf(acc[j][r] + bc, 0.f) * wv;
    }
    #pragma unroll
    for (int m = 1; m < 16; m <<= 1) {
        #pragma unroll
        for (int r = 0; r < 4; ++r) rsum[r] += __shfl_xor(rsum[r], m, 64);
    }
    if (fr == 0) {
        float bb = b2[0];
        #pragma unroll
        for (int r = 0; r < 4; ++r)
            out[m0 + wave * 16 + rq * 4 + r] = sigmoidf_(rsum[r] + bb);
    }
}

// =======================================================================================
extern "C" void kernel_launch(void* const* d_in, const int* in_sizes, int n_in,
                              void* d_out, int out_size, void* d_ws, size_t ws_size,
                              hipStream_t stream)
{
    const float* x     = (const float*)d_in[0];
    const float* ge    = (const float*)d_in[1];
    const int*   ei    = (const int*)d_in[2];
    const int*   batch = (const int*)d_in[4];
    const int*   he    = (const int*)d_in[5];
    const float* hw_w1 = (const float*)d_in[6];
    const float* hw_b1 = (const float*)d_in[7];
    const float* hw_w2 = (const float*)d_in[8];
    const float* hw_b2 = (const float*)d_in[9];
    const float* c1_w  = (const float*)d_in[10];
    const float* c1_b  = (const float*)d_in[11];
    const float* c2_w  = (const float*)d_in[12];
    const float* c2_b  = (const float*)d_in[13];
    const float* g_w1  = (const float*)d_in[14];
    const float* g_b1  = (const float*)d_in[15];
    const float* g_w2  = (const float*)d_in[16];
    const float* g_b2  = (const float*)d_in[17];
    const float* cl_w1 = (const float*)d_in[18];
    const float* cl_b1 = (const float*)d_in[19];
    const float* cl_w2 = (const float*)d_in[20];
    const float* cl_b2 = (const float*)d_in[21];
    const float* attn  = (const float*)d_in[22];
    float* out = (float*)d_out;

    char* ws = (char*)d_ws;
    size_t off = 0;
    auto alloc = [&](size_t nb) -> void* {
        off = (off + 255) & ~(size_t)255;
        void* p = ws + off;
        off += nb;
        return p;
    };
    // ---- zero region (one memset): D, Bcnt, rowCnt, colCur, rowCur ----
    float* D      = (float*)alloc((size_t)EDGES * 4);   // becomes Dinv in place
    int*   Bcnt   = (int*)  alloc((size_t)NODES * 4);
    int*   rowCnt = (int*)  alloc((size_t)EDGES * 4);
    int*   colCur = (int*)  alloc((size_t)NODES * 4);
    int*   rowCur = (int*)  alloc((size_t)EDGES * 4);
    size_t zero_end = off;
    // ---- other small arrays ----
    float* node_w = (float*)alloc((size_t)NODES * 4);
    float* Binv   = (float*)alloc((size_t)NODES * 4);
    int*   colOff = (int*)  alloc((size_t)(NODES + 1) * 4);
    int*   rowOff = (int*)  alloc((size_t)(EDGES + 1) * 4);
    int*   colList= (int*)  alloc((size_t)NNZ_ * 4);
    int*   rowList= (int*)  alloc((size_t)NNZ_ * 4);
    int*   partA  = (int*)  alloc(1024 * 4);
    int*   partB  = (int*)  alloc(1024 * 4);
    // bf16 conversions (~5 MB)
    __hip_bfloat16* xb    = (__hip_bfloat16*)alloc((size_t)NODES * FDIM * 2);
    __hip_bfloat16* geb   = (__hip_bfloat16*)alloc((size_t)512 * FDIM * 2);
    __hip_bfloat16* gw1t  = (__hip_bfloat16*)alloc((size_t)512 * 384 * 2);
    __hip_bfloat16* gw2t  = (__hip_bfloat16*)alloc((size_t)128 * 512 * 2);
    __hip_bfloat16* clw1t = (__hip_bfloat16*)alloc((size_t)128 * 256 * 2);
    // generator split tables (~33.5 MB)
    __hip_bfloat16* xa    = (__hip_bfloat16*)alloc((size_t)NODES * 512 * 2);
    __hip_bfloat16* xb2   = (__hip_bfloat16*)alloc((size_t)NODES * 512 * 2);
    __hip_bfloat16* gc    = (__hip_bfloat16*)alloc((size_t)512 * 512 * 2);
    // big buffers
    float* agg  = (float*)alloc((size_t)NODES * 256 * 4);                    // 16.4 MB
    __hip_bfloat16* oe1b = (__hip_bfloat16*)alloc((size_t)NODES * 256 * 2);  // 8.2 MB
    __hip_bfloat16* oe2  = (__hip_bfloat16*)alloc((size_t)NODES * 128 * 2);  // 4.1 MB
    __hip_bfloat16* er   = (__hip_bfloat16*)alloc((size_t)EDGES * 256 * 2);  // 131 MB
    // xl2 [EDGES][128] bf16 = 65.5 MB overlays first half of er (er dead after col_agg_er)
    __hip_bfloat16* xl2  = er;

    hipMemsetAsync(D, 0, zero_end, stream);   // zeroes D..rowCur (incl. align pads)

    hyperweight_k<<<NODES / 8, 128, 0, stream>>>(x, ge, batch, hw_w1, hw_b1, hw_w2, hw_b2, node_w);
    incidence_pass<<<NNZ_ / 256, 256, 0, stream>>>(he, node_w, D, Bcnt, rowCnt);
    inv_k<<<EDGES / 256, 256, 0, stream>>>(D, Bcnt, Binv);

    const int ncN = (NODES + 1023) / 1024;
    const int ncE = (EDGES + 1023) / 1024;
    reduce_chunks<<<ncN, 1024, 0, stream>>>(Bcnt, partA, NODES);
    scan_sums<<<1, 1024, 0, stream>>>(partA, ncN);
    scan_chunks<<<ncN, 1024, 0, stream>>>(Bcnt, partA, colOff, NODES);
    reduce_chunks<<<ncE, 1024, 0, stream>>>(rowCnt, partB, EDGES);
    scan_sums<<<1, 1024, 0, stream>>>(partB, ncE);
    scan_chunks<<<ncE, 1024, 0, stream>>>(rowCnt, partB, rowOff, EDGES);
    scatter_pass<<<NNZ_ / 256, 256, 0, stream>>>(he, colOff, rowOff, colCur, rowCur, colList, rowList);

    // bf16 conversions / weight transposes
    conv_bf16<<<(NODES * FDIM + 255) / 256, 256, 0, stream>>>(x, xb, NODES * FDIM);
    conv_bf16<<<(512 * FDIM + 255) / 256, 256, 0, stream>>>(ge, geb, 512 * FDIM);
    transpose_bf16<<<(384 * 512 + 255) / 256, 256, 0, stream>>>(g_w1, gw1t, 384, 512);
    transpose_bf16<<<(512 * 128 + 255) / 256, 256, 0, stream>>>(g_w2, gw2t, 512, 128);
    transpose_bf16<<<(256 * 128 + 255) / 256, 256, 0, stream>>>(cl_w1, clw1t, 256, 128);

    // generator split tables: xa = x@W[0:128], xb2 = x@W[128:256], gc = ge@W[256:384]
    xw_mfma<128, 384><<<dim3(NODES / 64, 4), 256, 0, stream>>>(xb, gw1t, xa);
    xw_mfma<128, 384><<<dim3(NODES / 64, 4), 256, 0, stream>>>(xb, gw1t + 128, xb2);
    xw_mfma<128, 384><<<dim3(512 / 64, 4), 256, 0, stream>>>(geb, gw1t + 256, gc);

    // conv1 (linear-commuted): oe1 = Binv ⊙ (agg1 @ c1_w)   [NODES,256] bf16
    col_gather_x<<<NODES, 128, 0, stream>>>(xb, ei, colOff, colList, agg);
    gemm_node<256, 256, true><<<dim3(NODES / 64, 4), 256, 0, stream>>>(agg, c1_w, Binv, oe1b);

    // conv2: er materialized, flat col-aggregation, oe2 = Binv ⊙ (agg2 @ c2_w)
    er_k<<<EDGES, 128, 0, stream>>>(oe1b, rowOff, rowList, D, c1_b, er);
    col_agg_er<<<NODES, 128, 0, stream>>>(er, colOff, colList, agg);
    gemm_node<256, 128, true><<<dim3(NODES / 64, 2), 256, 0, stream>>>(agg, c2_w, Binv, oe2);

    // fused generator L2 -> xl2 (overwrites er region; er is dead)
    gen2_mfma<<<EDGES / 64, 256, 0, stream>>>(xa, xb2, gc, g_b1, gw2t, g_b2, ei, batch, xl2);

    // fused classifier (GEMM + inline sij + final dot + sigmoid) -> out
    cls_mfma<<<EDGES / 64, 256, 0, stream>>>(xl2, oe2, geb, attn, clw1t, cl_b1, cl_w2, cl_b2,
                                             c2_b, ei, batch, rowOff, rowList, D, out);
}

// Round 10
// 731.115 us; speedup vs baseline: 4.9330x; 1.0539x over previous
//
#include <hip/hip_runtime.h>
#include <hip/hip_bf16.h>
#include <hip/hip_fp16.h>

#define NODES  16000
#define FDIM   128
#define EDGES  256000
#define NNZ_   512000

typedef __attribute__((ext_vector_type(8))) short bf16x8;
typedef __attribute__((ext_vector_type(8))) _Float16 f16x8;
typedef __attribute__((ext_vector_type(4))) float f32x4;

__device__ __forceinline__ float sigmoidf_(float z) { return 1.f / (1.f + __expf(-z)); }
__device__ __forceinline__ float bflo(unsigned u) { return __uint_as_float(u << 16); }
__device__ __forceinline__ float bfhi(unsigned u) { return __uint_as_float(u & 0xffff0000u); }
__device__ __forceinline__ unsigned pack2(float lo, float hi) {
    __hip_bfloat162 h;
    h.x = __float2bfloat16(lo);
    h.y = __float2bfloat16(hi);
    return *(unsigned*)&h;
}
__device__ __forceinline__ unsigned pk_add_f16(unsigned a, unsigned b) {
    unsigned r; asm("v_pk_add_f16 %0, %1, %2" : "=v"(r) : "v"(a), "v"(b)); return r;
}
__device__ __forceinline__ unsigned pk_relu_f16(unsigned a) {
    unsigned r; asm("v_pk_max_f16 %0, %1, %2" : "=v"(r) : "v"(a), "v"(0u)); return r;
}
__device__ __forceinline__ unsigned pkh(float lo, float hi) {
    __half2 h = __floats2half2_rn(lo, hi);
    return *(unsigned*)&h;
}
__device__ __forceinline__ float2 h2f2(unsigned u) {
    return __half22float2(*(__half2*)&u);
}

// ---------------- HyperWeight ----------------
__global__ __launch_bounds__(128) void hyperweight_k(
    const float* __restrict__ x, const float* __restrict__ ge, const int* __restrict__ batch,
    const float* __restrict__ w1, const float* __restrict__ b1,
    const float* __restrict__ w2, const float* __restrict__ b2, float* __restrict__ node_w)
{
    __shared__ float a[8][256];
    __shared__ float red[128];
    const int t = threadIdx.x;
    const int nb = blockIdx.x * 8;
    for (int u = 0; u < 8; ++u) {
        int n = nb + u;
        a[u][t]       = x[(size_t)n * FDIM + t];
        a[u][128 + t] = ge[(size_t)batch[n] * FDIM + t];
    }
    __syncthreads();
    float acc[8] = {0,0,0,0,0,0,0,0};
    for (int k = 0; k < 256; ++k) {
        float wv = w1[k * 128 + t];
        #pragma unroll
        for (int u = 0; u < 8; ++u) acc[u] += a[u][k] * wv;
    }
    const float wv2 = w2[t];
    for (int u = 0; u < 8; ++u) {
        float h = fmaxf(acc[u] + b1[t], 0.f);
        red[t] = h * wv2;
        __syncthreads();
        for (int s2 = 64; s2 > 0; s2 >>= 1) {
            if (t < s2) red[t] += red[t + s2];
            __syncthreads();
        }
        if (t == 0) node_w[nb + u] = sigmoidf_(red[0] + b2[0]);
        __syncthreads();
    }
}

// ---------------- incidence pass ----------------
__global__ void incidence_pass(const int* __restrict__ he, const float* __restrict__ node_w,
                               float* __restrict__ D, int* __restrict__ Bcnt, int* __restrict__ rowCnt)
{
    int i = blockIdx.x * 256 + threadIdx.x;
    if (i >= NNZ_) return;
    int hr = he[i];
    int hc = he[NNZ_ + i];
    int hc2 = he[NNZ_ + hc];              // repo quirk: w = node_w[hcol[hcol[i]]]
    atomicAdd(&D[hr], node_w[hc2]);
    atomicAdd(&Bcnt[hc], 1);
    atomicAdd(&rowCnt[hr], 1);
}

// fused: Dinv (edges) + Binv (nodes)
__global__ void inv_k(float* __restrict__ D, const int* __restrict__ Bcnt, float* __restrict__ Binv) {
    int i = blockIdx.x * 256 + threadIdx.x;
    if (i < EDGES) {
        float d = D[i];
        D[i] = (d != 0.f) ? 1.f / d : 0.f;
    }
    if (i < NODES) {
        int c = Bcnt[i];
        Binv[i] = c ? 1.f / (float)c : 0.f;
    }
}

// ---------------- exclusive scan (3-kernel) ----------------
__global__ __launch_bounds__(1024) void reduce_chunks(const int* __restrict__ in, int* __restrict__ part, int n) {
    __shared__ int s[1024];
    int t = threadIdx.x, g = blockIdx.x * 1024 + t;
    s[t] = (g < n) ? in[g] : 0;
    __syncthreads();
    for (int d = 512; d > 0; d >>= 1) {
        if (t < d) s[t] += s[t + d];
        __syncthreads();
    }
    if (t == 0) part[blockIdx.x] = s[0];
}
__global__ __launch_bounds__(1024) void scan_sums(int* __restrict__ part, int nc) {
    __shared__ int s[1024];
    int t = threadIdx.x;
    int v = (t < nc) ? part[t] : 0;
    s[t] = v;
    __syncthreads();
    for (int d = 1; d < 1024; d <<= 1) {
        int tv = (t >= d) ? s[t - d] : 0;
        __syncthreads();
        s[t] += tv;
        __syncthreads();
    }
    if (t < nc) part[t] = s[t] - v;     // exclusive
}
__global__ __launch_bounds__(1024) void scan_chunks(const int* __restrict__ in, const int* __restrict__ part,
                                                    int* __restrict__ out, int n) {
    __shared__ int s[1024];
    int t = threadIdx.x, g = blockIdx.x * 1024 + t;
    int v = (g < n) ? in[g] : 0;
    s[t] = v;
    __syncthreads();
    for (int d = 1; d < 1024; d <<= 1) {
        int tv = (t >= d) ? s[t - d] : 0;
        __syncthreads();
        s[t] += tv;
        __syncthreads();
    }
    int excl = s[t] - v + part[blockIdx.x];
    if (g < n) out[g] = excl;
    if (g == n - 1) out[n] = excl + v;
}

// ---------------- scatter into CSR lists ----------------
__global__ void scatter_pass(const int* __restrict__ he, const int* __restrict__ colOff, const int* __restrict__ rowOff,
                             int* __restrict__ colCur, int* __restrict__ rowCur,
                             int* __restrict__ colList, int* __restrict__ rowList)
{
    int i = blockIdx.x * 256 + threadIdx.x;
    if (i >= NNZ_) return;
    int hr = he[i];
    int hc = he[NNZ_ + i];
    int p = colOff[hc] + atomicAdd(&colCur[hc], 1);
    colList[p] = hr;
    int q = rowOff[hr] + atomicAdd(&rowCur[hr], 1);
    rowList[q] = hc;
}

// ---------------- conversion helpers ----------------
__global__ void conv_x(const float* __restrict__ in, __hip_bfloat16* __restrict__ ob,
                       _Float16* __restrict__ oh, int n) {
    int i = blockIdx.x * 256 + threadIdx.x;
    if (i < n) { float v = in[i]; ob[i] = __float2bfloat16(v); oh[i] = (_Float16)v; }
}
__global__ void conv_f16(const float* __restrict__ in, _Float16* __restrict__ out, int n) {
    int i = blockIdx.x * 256 + threadIdx.x;
    if (i < n) out[i] = (_Float16)in[i];
}
// in [K][N] fp32 -> out [N][K] fp16
__global__ void transpose_f16(const float* __restrict__ in, _Float16* __restrict__ out, int K, int N) {
    int i = blockIdx.x * 256 + threadIdx.x;
    if (i >= K * N) return;
    int n = i / K, k = i - n * K;
    out[i] = (_Float16)in[k * N + n];
}

// ---------------- agg1[n,256] = sum over edges r in col(n) of [xb[ei0[r]] | xb[ei1[r]]] ----
__global__ __launch_bounds__(128) void col_gather_x(
    const __hip_bfloat16* __restrict__ xb, const int* __restrict__ ei,
    const int* __restrict__ colOff, const int* __restrict__ colList, float* __restrict__ agg)
{
    int n = blockIdx.x;
    int t = threadIdx.x;
    int base = (t < 64) ? 0 : EDGES;
    int f = t & 63;
    const unsigned* x32 = (const unsigned*)xb;
    int s = colOff[n], e = colOff[n + 1];
    float vx = 0.f, vy = 0.f;
    int j = s;
    for (; j + 3 < e; j += 4) {
        int r0 = colList[j], r1 = colList[j + 1], r2 = colList[j + 2], r3 = colList[j + 3];
        unsigned q0 = x32[(size_t)ei[base + r0] * 64 + f];
        unsigned q1 = x32[(size_t)ei[base + r1] * 64 + f];
        unsigned q2 = x32[(size_t)ei[base + r2] * 64 + f];
        unsigned q3 = x32[(size_t)ei[base + r3] * 64 + f];
        vx += bflo(q0) + bflo(q1) + bflo(q2) + bflo(q3);
        vy += bfhi(q0) + bfhi(q1) + bfhi(q2) + bfhi(q3);
    }
    for (; j < e; ++j) {
        unsigned q0 = x32[(size_t)ei[base + colList[j]] * 64 + f];
        vx += bflo(q0); vy += bfhi(q0);
    }
    int ob = (t < 64) ? 0 : 128;
    float2 o = make_float2(vx, vy);
    *(float2*)(agg + (size_t)n * 256 + ob + 2 * f) = o;
}

// ---------------- er[r,256] (bf16) = sigmoid(Dinv[r]*rowsum(oe1) + c1_b) ----------------
__global__ __launch_bounds__(128) void er_k(
    const __hip_bfloat16* __restrict__ oe1, const int* __restrict__ rowOff,
    const int* __restrict__ rowList, const float* __restrict__ Dinv,
    const float* __restrict__ c1b, __hip_bfloat16* __restrict__ er)
{
    int r = blockIdx.x;
    int t = threadIdx.x;
    int s = rowOff[r], e = rowOff[r + 1];
    const unsigned* o32 = (const unsigned*)oe1;
    float vx = 0.f, vy = 0.f;
    int j = s;
    for (; j + 1 < e; j += 2) {
        unsigned q0 = o32[(size_t)rowList[j] * 128 + t];
        unsigned q1 = o32[(size_t)rowList[j + 1] * 128 + t];
        vx += bflo(q0) + bflo(q1);
        vy += bfhi(q0) + bfhi(q1);
    }
    if (j < e) {
        unsigned q0 = o32[(size_t)rowList[j] * 128 + t];
        vx += bflo(q0); vy += bfhi(q0);
    }
    float dv = Dinv[r];
    *(unsigned*)(er + (size_t)r * 256 + 2 * t) =
        pack2(sigmoidf_(dv * vx + c1b[2 * t]), sigmoidf_(dv * vy + c1b[2 * t + 1]));
}

// ---------------- agg2[n,256] = sum over r in col(n) of er[r] ----------------
__global__ __launch_bounds__(128) void col_agg_er(
    const __hip_bfloat16* __restrict__ er, const int* __restrict__ colOff,
    const int* __restrict__ colList, float* __restrict__ agg)
{
    int n = blockIdx.x;
    int t = threadIdx.x;
    const unsigned* e32 = (const unsigned*)er;
    int s = colOff[n], e = colOff[n + 1];
    float vx = 0.f, vy = 0.f;
    int j = s;
    for (; j + 3 < e; j += 4) {
        unsigned q0 = e32[(size_t)colList[j]     * 128 + t];
        unsigned q1 = e32[(size_t)colList[j + 1] * 128 + t];
        unsigned q2 = e32[(size_t)colList[j + 2] * 128 + t];
        unsigned q3 = e32[(size_t)colList[j + 3] * 128 + t];
        vx += bflo(q0) + bflo(q1) + bflo(q2) + bflo(q3);
        vy += bfhi(q0) + bfhi(q1) + bfhi(q2) + bfhi(q3);
    }
    for (; j < e; ++j) {
        unsigned q0 = e32[(size_t)colList[j] * 128 + t];
        vx += bflo(q0); vy += bfhi(q0);
    }
    float2 o = make_float2(vx, vy);
    *(float2*)(agg + (size_t)n * 256 + 2 * t) = o;
}

// ---------------- node-rows fp32 GEMM: C = rowscale ⊙ (A @ B) ----------------
template<int K, int NN, bool OB16>
__global__ __launch_bounds__(256) void gemm_node(
    const float* __restrict__ A, const float* __restrict__ B,
    const float* __restrict__ rowscale, void* __restrict__ C)
{
    __shared__ float As[16][68];
    __shared__ float Bs[16][68];
    const int tid = threadIdx.x;
    const int m0 = blockIdx.x * 64, n0 = blockIdx.y * 64;
    const int la_k = tid & 15, la_m = tid >> 4;
    const int lb_n = tid & 63, lb_k = tid >> 6;
    const int tn = tid & 15, tm = tid >> 4;
    float acc[4][4] = {};
    for (int k0 = 0; k0 < K; k0 += 16) {
        #pragma unroll
        for (int r = 0; r < 4; ++r)
            As[la_k][la_m + 16 * r] = A[(size_t)(m0 + la_m + 16 * r) * K + k0 + la_k];
        #pragma unroll
        for (int r = 0; r < 4; ++r)
            Bs[lb_k + 4 * r][lb_n] = B[(size_t)(k0 + lb_k + 4 * r) * NN + n0 + lb_n];
        __syncthreads();
        #pragma unroll
        for (int kk = 0; kk < 16; ++kk) {
            float4 av = *(const float4*)&As[kk][tm * 4];
            float4 bv = *(const float4*)&Bs[kk][tn * 4];
            float am[4] = {av.x, av.y, av.z, av.w};
            float bn[4] = {bv.x, bv.y, bv.z, bv.w};
            #pragma unroll
            for (int i = 0; i < 4; ++i)
                #pragma unroll
                for (int j = 0; j < 4; ++j)
                    acc[i][j] += am[i] * bn[j];
        }
        __syncthreads();
    }
    #pragma unroll
    for (int i = 0; i < 4; ++i) {
        int m = m0 + tm * 4 + i;
        float rs = rowscale[m];
        if constexpr (OB16) {
            __hip_bfloat16* Cp = (__hip_bfloat16*)C + (size_t)m * NN + n0 + tn * 4;
            #pragma unroll
            for (int j = 0; j < 4; ++j) Cp[j] = __float2bfloat16(rs * acc[i][j]);
        } else {
            float4 o = make_float4(rs * acc[i][0], rs * acc[i][1], rs * acc[i][2], rs * acc[i][3]);
            *(float4*)((float*)C + (size_t)m * NN + n0 + tn * 4) = o;
        }
    }
}

// ---------------- fp16 MFMA GEMM, 64x128 tile: dst[M][512] (optionally + gc[batch]+b1) ------
template<int LDB, bool XAG>
__global__ __launch_bounds__(256) void xw_f16(
    const _Float16* __restrict__ A, const _Float16* __restrict__ Bt, _Float16* __restrict__ dst,
    const _Float16* __restrict__ gct, const int* __restrict__ batch, const float* __restrict__ bias)
{
    __shared__ __align__(16) _Float16 As[64][40];
    __shared__ __align__(16) _Float16 Bs[128][40];
    const int tid = threadIdx.x;
    const int m0 = blockIdx.x * 64, n0 = blockIdx.y * 128;
    const int wave = tid >> 6, lane = tid & 63;
    const int wr = wave >> 1, wc = wave & 1;
    const int srow = tid >> 2, kseg = (tid & 3) * 8;
    const int nr = tid >> 1, kb = (tid & 1) * 16;
    const int fr = lane & 15, krow = (lane >> 4) * 8, rq = lane >> 4;

    f32x4 acc[2][4] = {};
    for (int k0 = 0; k0 < 128; k0 += 32) {
        *(uint4*)&As[srow][kseg] = *(const uint4*)(A + (size_t)(m0 + srow) * 128 + k0 + kseg);
        *(uint4*)&Bs[nr][kb]     = *(const uint4*)(Bt + (size_t)(n0 + nr) * LDB + k0 + kb);
        *(uint4*)&Bs[nr][kb + 8] = *(const uint4*)(Bt + (size_t)(n0 + nr) * LDB + k0 + kb + 8);
        __syncthreads();
        f16x8 af[2], bf[4];
        #pragma unroll
        for (int i = 0; i < 2; ++i) af[i] = *(const f16x8*)&As[wr * 32 + i * 16 + fr][krow];
        #pragma unroll
        for (int j = 0; j < 4; ++j) bf[j] = *(const f16x8*)&Bs[wc * 64 + j * 16 + fr][krow];
        #pragma unroll
        for (int i = 0; i < 2; ++i)
            #pragma unroll
            for (int j = 0; j < 4; ++j)
                acc[i][j] = __builtin_amdgcn_mfma_f32_16x16x32_f16(af[i], bf[j], acc[i][j], 0, 0, 0);
        __syncthreads();
    }
    #pragma unroll
    for (int i = 0; i < 2; ++i)
        #pragma unroll
        for (int j = 0; j < 4; ++j) {
            int col = n0 + wc * 64 + j * 16 + fr;
            #pragma unroll
            for (int r = 0; r < 4; ++r) {
                int row = m0 + wr * 32 + i * 16 + rq * 4 + r;
                float v = acc[i][j][r];
                if constexpr (XAG)
                    v += (float)gct[(size_t)batch[row] * 512 + col] + bias[col];
                dst[(size_t)row * 512 + col] = (_Float16)v;
            }
        }
}

// ---------------- fused generator-L2 + classifier (fp16 path) ----------------
// xl = relu(relu(xag[col]+xb2[row]) @ gw2t + g_b2)        (kept in LDS)
// out = sigmoid( relu([a0*xl + a1*sij_inline | geh[gi]] @ clw1t + cl_b1)·w2 + cl_b2 )
__global__ __launch_bounds__(256) void gencls_mfma(
    const _Float16* __restrict__ xag, const _Float16* __restrict__ xb2,
    const _Float16* __restrict__ gw2t, const float* __restrict__ gb2,
    const _Float16* __restrict__ geh, const float* __restrict__ attn,
    const _Float16* __restrict__ clw1t, const float* __restrict__ clb1,
    const float* __restrict__ w2, const float* __restrict__ b2, const float* __restrict__ c2b,
    const __hip_bfloat16* __restrict__ oe2,
    const int* __restrict__ ei, const int* __restrict__ batch,
    const int* __restrict__ rowOff, const int* __restrict__ rowList, const float* __restrict__ Dinv,
    float* __restrict__ out)
{
    __shared__ __align__(16) _Float16 As[64][40];
    __shared__ __align__(16) _Float16 Bs[128][40];
    __shared__ __align__(16) _Float16 xlt[64][128];
    const int tid = threadIdx.x;
    const int m0 = blockIdx.x * 64;
    const int wave = tid >> 6, lane = tid & 63;
    const int wr = wave >> 1, wc = wave & 1;
    const int srow = tid >> 2, kseg = (tid & 3) * 8;
    const int nr = tid >> 1, kb = (tid & 1) * 16;
    const int fr = lane & 15, krow = (lane >> 4) * 8, rq = lane >> 4;

    const int eg = m0 + srow;
    const int cnode = ei[eg];
    const _Float16* pa = xag + (size_t)cnode * 512;
    const _Float16* pb = xb2 + (size_t)ei[EDGES + eg] * 512;
    const int gi = batch[cnode];
    const int rs = rowOff[eg], re = rowOff[eg + 1];
    const float dv = Dinv[eg];

    // ---- phase 1: generator L2 GEMM (K=512) ----
    f32x4 acc[2][4] = {};
    for (int k0 = 0; k0 < 512; k0 += 32) {
        int kg = k0 + kseg;
        uint4 ua = *(const uint4*)(pa + kg);
        uint4 ub = *(const uint4*)(pb + kg);
        uint4 av;
        av.x = pk_relu_f16(pk_add_f16(ua.x, ub.x));
        av.y = pk_relu_f16(pk_add_f16(ua.y, ub.y));
        av.z = pk_relu_f16(pk_add_f16(ua.z, ub.z));
        av.w = pk_relu_f16(pk_add_f16(ua.w, ub.w));
        *(uint4*)&As[srow][kseg] = av;
        *(uint4*)&Bs[nr][kb]     = *(const uint4*)(gw2t + (size_t)nr * 512 + k0 + kb);
        *(uint4*)&Bs[nr][kb + 8] = *(const uint4*)(gw2t + (size_t)nr * 512 + k0 + kb + 8);
        __syncthreads();
        f16x8 af[2], bf[4];
        #pragma unroll
        for (int i = 0; i < 2; ++i) af[i] = *(const f16x8*)&As[wr * 32 + i * 16 + fr][krow];
        #pragma unroll
        for (int j = 0; j < 4; ++j) bf[j] = *(const f16x8*)&Bs[wc * 64 + j * 16 + fr][krow];
        #pragma unroll
        for (int i = 0; i < 2; ++i)
            #pragma unroll
            for (int j = 0; j < 4; ++j)
                acc[i][j] = __builtin_amdgcn_mfma_f32_16x16x32_f16(af[i], bf[j], acc[i][j], 0, 0, 0);
        __syncthreads();
    }
    // xl tile -> LDS (relu + bias)
    #pragma unroll
    for (int i = 0; i < 2; ++i)
        #pragma unroll
        for (int j = 0; j < 4; ++j) {
            int col = wc * 64 + j * 16 + fr;
            float bc = gb2[col];
            #pragma unroll
            for (int r = 0; r < 4; ++r) {
                int row = wr * 32 + i * 16 + rq * 4 + r;
                xlt[row][col] = (_Float16)fmaxf(acc[i][j][r] + bc, 0.f);
            }
        }
    __syncthreads();

    // ---- phase 2: classifier GEMM (K=256) + fused dot ----
    const float a0 = attn[0], a1 = attn[1];
    f32x4 acc2[8] = {};
    for (int it = 0; it < 8; ++it) {
        int k0 = it * 32, kg = k0 + kseg;
        uint4 av;
        if (kg < 128) {
            uint4 u = *(const uint4*)&xlt[srow][kg];
            float s0 = 0.f, s1 = 0.f, s2 = 0.f, s3 = 0.f, s4 = 0.f, s5 = 0.f, s6 = 0.f, s7 = 0.f;
            for (int q = rs; q < re; ++q) {
                uint4 o = *(const uint4*)(oe2 + (size_t)rowList[q] * 128 + kg);
                s0 += bflo(o.x); s1 += bfhi(o.x); s2 += bflo(o.y); s3 += bfhi(o.y);
                s4 += bflo(o.z); s5 += bfhi(o.z); s6 += bflo(o.w); s7 += bfhi(o.w);
            }
            float4 c0 = *(const float4*)(c2b + kg);
            float4 c1 = *(const float4*)(c2b + kg + 4);
            float2 f0 = h2f2(u.x), f1 = h2f2(u.y), f2 = h2f2(u.z), f3 = h2f2(u.w);
            av.x = pkh(a0 * f0.x + a1 * sigmoidf_(dv * s0 + c0.x),
                       a0 * f0.y + a1 * sigmoidf_(dv * s1 + c0.y));
            av.y = pkh(a0 * f1.x + a1 * sigmoidf_(dv * s2 + c0.z),
                       a0 * f1.y + a1 * sigmoidf_(dv * s3 + c0.w));
            av.z = pkh(a0 * f2.x + a1 * sigmoidf_(dv * s4 + c1.x),
                       a0 * f2.y + a1 * sigmoidf_(dv * s5 + c1.y));
            av.w = pkh(a0 * f3.x + a1 * sigmoidf_(dv * s6 + c1.z),
                       a0 * f3.y + a1 * sigmoidf_(dv * s7 + c1.w));
        } else {
            av = *(const uint4*)(geh + (size_t)gi * 128 + kg - 128);
        }
        *(uint4*)&As[srow][kseg] = av;
        *(uint4*)&Bs[nr][kb]     = *(const uint4*)(clw1t + (size_t)nr * 256 + k0 + kb);
        *(uint4*)&Bs[nr][kb + 8] = *(const uint4*)(clw1t + (size_t)nr * 256 + k0 + kb + 8);
        __syncthreads();
        f16x8 af = *(const f16x8*)&As[wave * 16 + fr][krow];
        #pragma unroll
        for (int j = 0; j < 8; ++j) {
            f16x8 bf = *(const f16x8*)&Bs[j * 16 + fr][krow];
            acc2[j] = __builtin_amdgcn_mfma_f32_16x16x32_f16(af, bf, acc2[j], 0, 0, 0);
        }
        __syncthreads();
    }
    // epilogue: relu(+clb1), dot w2, 16-lane reduce, sigmoid
    float rsum[4] = {0.f, 0.f, 0.f, 0.f};
    #pragma unroll
    for (int j = 0; j < 8; ++j) {
        int colg = j * 16 + fr;
        float bc = clb1[colg];
        float wv = w2[colg];
        #pragma unroll
        for (int r = 0; r < 4; ++r)
            rsum[r] += fmaxf(acc2[j][r] + bc, 0.f) * wv;
    }
    #pragma unroll
    for (int m = 1; m < 16; m <<= 1) {
        #pragma unroll
        for (int r = 0; r < 4; ++r) rsum[r] += __shfl_xor(rsum[r], m, 64);
    }
    if (fr == 0) {
        float bb = b2[0];
        #pragma unroll
        for (int r = 0; r < 4; ++r)
            out[m0 + wave * 16 + rq * 4 + r] = sigmoidf_(rsum[r] + bb);
    }
}

// =======================================================================================
extern "C" void kernel_launch(void* const* d_in, const int* in_sizes, int n_in,
                              void* d_out, int out_size, void* d_ws, size_t ws_size,
                              hipStream_t stream)
{
    const float* x     = (const float*)d_in[0];
    const float* ge    = (const float*)d_in[1];
    const int*   ei    = (const int*)d_in[2];
    const int*   batch = (const int*)d_in[4];
    const int*   he    = (const int*)d_in[5];
    const float* hw_w1 = (const float*)d_in[6];
    const float* hw_b1 = (const float*)d_in[7];
    const float* hw_w2 = (const float*)d_in[8];
    const float* hw_b2 = (const float*)d_in[9];
    const float* c1_w  = (const float*)d_in[10];
    const float* c1_b  = (const float*)d_in[11];
    const float* c2_w  = (const float*)d_in[12];
    const float* c2_b  = (const float*)d_in[13];
    const float* g_w1  = (const float*)d_in[14];
    const float* g_b1  = (const float*)d_in[15];
    const float* g_w2  = (const float*)d_in[16];
    const float* g_b2  = (const float*)d_in[17];
    const float* cl_w1 = (const float*)d_in[18];
    const float* cl_b1 = (const float*)d_in[19];
    const float* cl_w2 = (const float*)d_in[20];
    const float* cl_b2 = (const float*)d_in[21];
    const float* attn  = (const float*)d_in[22];
    float* out = (float*)d_out;

    char* ws = (char*)d_ws;
    size_t off = 0;
    auto alloc = [&](size_t nb) -> void* {
        off = (off + 255) & ~(size_t)255;
        void* p = ws + off;
        off += nb;
        return p;
    };
    // ---- zero region (one memset): D, Bcnt, rowCnt, colCur, rowCur ----
    float* D      = (float*)alloc((size_t)EDGES * 4);   // becomes Dinv in place
    int*   Bcnt   = (int*)  alloc((size_t)NODES * 4);
    int*   rowCnt = (int*)  alloc((size_t)EDGES * 4);
    int*   colCur = (int*)  alloc((size_t)NODES * 4);
    int*   rowCur = (int*)  alloc((size_t)EDGES * 4);
    size_t zero_end = off;
    // ---- other small arrays ----
    float* node_w = (float*)alloc((size_t)NODES * 4);
    float* Binv   = (float*)alloc((size_t)NODES * 4);
    int*   colOff = (int*)  alloc((size_t)(NODES + 1) * 4);
    int*   rowOff = (int*)  alloc((size_t)(EDGES + 1) * 4);
    int*   colList= (int*)  alloc((size_t)NNZ_ * 4);
    int*   rowList= (int*)  alloc((size_t)NNZ_ * 4);
    int*   partA  = (int*)  alloc(1024 * 4);
    int*   partB  = (int*)  alloc(1024 * 4);
    // dtype tables (~10 MB)
    __hip_bfloat16* xb    = (__hip_bfloat16*)alloc((size_t)NODES * FDIM * 2);
    _Float16* xh    = (_Float16*)alloc((size_t)NODES * FDIM * 2);
    _Float16* geh   = (_Float16*)alloc((size_t)512 * FDIM * 2);
    _Float16* gw1t  = (_Float16*)alloc((size_t)512 * 384 * 2);
    _Float16* gw2t  = (_Float16*)alloc((size_t)128 * 512 * 2);
    _Float16* clw1t = (_Float16*)alloc((size_t)128 * 256 * 2);
    // generator split tables (~33.5 MB)
    _Float16* xag   = (_Float16*)alloc((size_t)NODES * 512 * 2);
    _Float16* xb2   = (_Float16*)alloc((size_t)NODES * 512 * 2);
    _Float16* gc    = (_Float16*)alloc((size_t)512 * 512 * 2);
    // big buffers
    float* agg  = (float*)alloc((size_t)NODES * 256 * 4);                    // 16.4 MB
    __hip_bfloat16* oe1b = (__hip_bfloat16*)alloc((size_t)NODES * 256 * 2);  // 8.2 MB
    __hip_bfloat16* oe2  = (__hip_bfloat16*)alloc((size_t)NODES * 128 * 2);  // 4.1 MB
    __hip_bfloat16* er   = (__hip_bfloat16*)alloc((size_t)EDGES * 256 * 2);  // 131 MB

    hipMemsetAsync(D, 0, zero_end, stream);   // zeroes D..rowCur (incl. align pads)

    hyperweight_k<<<NODES / 8, 128, 0, stream>>>(x, ge, batch, hw_w1, hw_b1, hw_w2, hw_b2, node_w);
    incidence_pass<<<NNZ_ / 256, 256, 0, stream>>>(he, node_w, D, Bcnt, rowCnt);
    inv_k<<<EDGES / 256, 256, 0, stream>>>(D, Bcnt, Binv);

    const int ncN = (NODES + 1023) / 1024;
    const int ncE = (EDGES + 1023) / 1024;
    reduce_chunks<<<ncN, 1024, 0, stream>>>(Bcnt, partA, NODES);
    scan_sums<<<1, 1024, 0, stream>>>(partA, ncN);
    scan_chunks<<<ncN, 1024, 0, stream>>>(Bcnt, partA, colOff, NODES);
    reduce_chunks<<<ncE, 1024, 0, stream>>>(rowCnt, partB, EDGES);
    scan_sums<<<1, 1024, 0, stream>>>(partB, ncE);
    scan_chunks<<<ncE, 1024, 0, stream>>>(rowCnt, partB, rowOff, EDGES);
    scatter_pass<<<NNZ_ / 256, 256, 0, stream>>>(he, colOff, rowOff, colCur, rowCur, colList, rowList);

    // conversions / weight transposes (fp16 generator+classifier path)
    conv_x<<<(NODES * FDIM + 255) / 256, 256, 0, stream>>>(x, xb, xh, NODES * FDIM);
    conv_f16<<<(512 * FDIM + 255) / 256, 256, 0, stream>>>(ge, geh, 512 * FDIM);
    transpose_f16<<<(384 * 512 + 255) / 256, 256, 0, stream>>>(g_w1, gw1t, 384, 512);
    transpose_f16<<<(512 * 128 + 255) / 256, 256, 0, stream>>>(g_w2, gw2t, 512, 128);
    transpose_f16<<<(256 * 128 + 255) / 256, 256, 0, stream>>>(cl_w1, clw1t, 256, 128);

    // generator split tables: gc = ge@W[256:384]; xag = x@W[0:128] + gc[batch] + b1; xb2 = x@W[128:256]
    xw_f16<384, false><<<dim3(512 / 64, 4), 256, 0, stream>>>(geh, gw1t + 256, gc, nullptr, nullptr, nullptr);
    xw_f16<384, true><<<dim3(NODES / 64, 4), 256, 0, stream>>>(xh, gw1t, xag, gc, batch, g_b1);
    xw_f16<384, false><<<dim3(NODES / 64, 4), 256, 0, stream>>>(xh, gw1t + 128, xb2, nullptr, nullptr, nullptr);

    // conv1 (linear-commuted): oe1 = Binv ⊙ (agg1 @ c1_w)   [NODES,256] bf16
    col_gather_x<<<NODES, 128, 0, stream>>>(xb, ei, colOff, colList, agg);
    gemm_node<256, 256, true><<<dim3(NODES / 64, 4), 256, 0, stream>>>(agg, c1_w, Binv, oe1b);

    // conv2: er materialized, flat col-aggregation, oe2 = Binv ⊙ (agg2 @ c2_w)
    er_k<<<EDGES, 128, 0, stream>>>(oe1b, rowOff, rowList, D, c1_b, er);
    col_agg_er<<<NODES, 128, 0, stream>>>(er, colOff, colList, agg);
    gemm_node<256, 128, true><<<dim3(NODES / 64, 2), 256, 0, stream>>>(agg, c2_w, Binv, oe2);

    // fused generator-L2 + classifier -> out
    gencls_mfma<<<EDGES / 64, 256, 0, stream>>>(xag, xb2, gw2t, g_b2, geh, attn, clw1t, cl_b1,
                                                cl_w2, cl_b2, c2_b, oe2, ei, batch,
                                                rowOff, rowList, D, out);
}